// Round 15
// baseline (2456.045 us; speedup 1.0000x reference)
//
#include <hip/hip_runtime.h>
#include <hip/hip_bf16.h>

typedef __hip_bfloat16 bf16;
typedef __attribute__((ext_vector_type(8))) short bf16x8;
typedef __attribute__((ext_vector_type(4))) float f32x4;

#define B_   16
#define T_   500
#define D_   768
#define NH_  12
#define DH_  64
#define FFN_ 3072
#define QKVS 2304

__device__ __forceinline__ float bfu2f(unsigned short u){ return __uint_as_float(((unsigned)u)<<16); }
__device__ __forceinline__ float geluf(float x){ return 0.5f*x*(1.0f + erff(x*0.70710678118654752f)); }

__device__ __forceinline__ float4 ld4f(const float* p){ return *reinterpret_cast<const float4*>(p); }
__device__ __forceinline__ float4 ld4f(const bf16* p){
  ushort4 u = *reinterpret_cast<const ushort4*>(p);
  return make_float4(bfu2f(u.x), bfu2f(u.y), bfu2f(u.z), bfu2f(u.w));
}

// async global->LDS, 16 bytes per lane (dst must be wave-uniform base + lane*16)
__device__ __forceinline__ void gload_lds16(const bf16* g, uint4* l){
  __builtin_amdgcn_global_load_lds(
      (const __attribute__((address_space(1))) void*)g,
      (__attribute__((address_space(3))) void*)l, 16, 0, 0);
}

// ---------------- conv1: Cin=1, 32 oc per thread, writes NHWC [b][96][500][32] ----------------
__global__ __launch_bounds__(256) void conv1_k(const float* __restrict__ spec,
    const float* __restrict__ w, const float* __restrict__ bias, bf16* __restrict__ out)
{
  const int pos = blockIdx.x*256 + threadIdx.x;
  if (pos >= B_*96*500) return;
  const int x  = pos % 500;
  const int yo = (pos/500) % 96;
  const int b  = pos/(500*96);
  const float* ip = spec + (size_t)b*192*500;

  float v[6][5];
  #pragma unroll
  for (int r = 0; r < 6; r++){
    const int yy = 2*yo - 2 + r;
    const bool vy = (yy >= 0) && (yy < 192);
    const float* rp = ip + (size_t)(vy ? yy : 0)*500;
    #pragma unroll
    for (int c = 0; c < 5; c++){
      const int xx = x - 2 + c;
      v[r][c] = (vy && xx >= 0 && xx < 500) ? rp[xx] : 0.f;
    }
  }

  const size_t obase = (((size_t)(b*96 + yo))*500 + x)*32;
  #pragma unroll
  for (int oc = 0; oc < 32; oc++){
    float a0 = bias[oc], a1 = bias[oc];
    #pragma unroll
    for (int r = 0; r < 5; r++)
      #pragma unroll
      for (int c = 0; c < 5; c++){
        const float wv = w[oc*25 + r*5 + c];
        a0 = fmaf(v[r][c],   wv, a0);
        a1 = fmaf(v[r+1][c], wv, a1);
      }
    out[obase + oc] = __float2bfloat16(fmaxf(geluf(a0), geluf(a1)));
  }
}

// ---------------- conv weight repack: OIHW fp32 -> bf16 [tap][cg][nf][lane][8] ----------------
template<int CIN>
__global__ __launch_bounds__(256) void conv_wt_k(const float* __restrict__ w, bf16* __restrict__ wt)
{
  const int e = blockIdx.x*256 + threadIdx.x;
  if (e >= 25*CIN*64) return;
  const int j    = e & 7;
  const int lane = (e >> 3) & 63;
  const int nf   = (e >> 9) & 3;
  const int t3   = e >> 11;
  const int cg   = t3 % (CIN/32);
  const int tap  = t3 / (CIN/32);
  const int oc = nf*16 + (lane & 15);
  const int ci = cg*32 + (lane >> 4)*8 + j;
  wt[e] = __float2bfloat16(w[(size_t)(oc*CIN + ci)*25 + tap]);
}

// ---------------- MFMA conv + GELU + pool, NHWC, LDS-staged branch-free inner loop ----------------
template<int CIN>
__global__ __launch_bounds__(256) void conv_mfma_k(const bf16* __restrict__ in,
    const bf16* __restrict__ wt, const float* __restrict__ bias,
    bf16* __restrict__ out, int Hin)
{
  constexpr int KB   = CIN/8;
  constexpr int ROWB = 68*CIN*2;
  __shared__ uint4 ldsu[6*68*CIN/8];
  char* lds = (char*)ldsu;

  const int Hout = Hin >> 1;
  const int x0 = blockIdx.x * 64;
  const int yo = blockIdx.y % Hout;
  const int b  = blockIdx.y / Hout;
  const int tid = threadIdx.x, w = tid >> 6, lane = tid & 63;
  const int lr = lane & 15, kb = lane >> 4;

  for (int idx = tid; idx < 6*68*KB; idx += 256){
    const int kbb = idx % KB;
    const int xx  = (idx/KB) % 68;
    const int r   = idx/(KB*68);
    const int yy = 2*yo + r - 2;
    const int xg = x0 + xx - 2;
    uint4 v = make_uint4(0,0,0,0);
    if (yy >= 0 && yy < Hin && xg >= 0 && xg < 500)
      v = *reinterpret_cast<const uint4*>(in + (((size_t)(b*Hin + yy))*500 + xg)*CIN + kbb*8);
    int off = r*ROWB + xx*(CIN*2) + kbb*16;
    off ^= (xx & 7) << 4;
    *reinterpret_cast<uint4*>(lds + off) = v;
  }
  __syncthreads();

  f32x4 acc0[4], acc1[4];
  #pragma unroll
  for (int nf = 0; nf < 4; nf++){ acc0[nf] = (f32x4){0,0,0,0}; acc1[nf] = (f32x4){0,0,0,0}; }

  const int xl = w*16 + lr;
  #pragma unroll
  for (int ky = 0; ky < 5; ky++){
    #pragma unroll
    for (int kx = 0; kx < 5; kx++){
      const int xx = xl + kx;
      const int tap = ky*5 + kx;
      #pragma unroll
      for (int cg = 0; cg < CIN/32; cg++){
        int aoff = ky*ROWB + xx*(CIN*2) + (cg*32 + kb*8)*2;
        aoff ^= (xx & 7) << 4;
        const bf16x8 a0 = *reinterpret_cast<const bf16x8*>(lds + aoff);
        const bf16x8 a1 = *reinterpret_cast<const bf16x8*>(lds + aoff + ROWB);
        const bf16* bp = wt + ((size_t)((tap*(CIN/32) + cg)*4)*64 + lane)*8;
        #pragma unroll
        for (int nf = 0; nf < 4; nf++){
          const bf16x8 bf_ = *reinterpret_cast<const bf16x8*>(bp + nf*512);
          acc0[nf] = __builtin_amdgcn_mfma_f32_16x16x32_bf16(a0, bf_, acc0[nf], 0, 0, 0);
          acc1[nf] = __builtin_amdgcn_mfma_f32_16x16x32_bf16(a1, bf_, acc1[nf], 0, 0, 0);
        }
      }
    }
  }

  #pragma unroll
  for (int rg = 0; rg < 4; rg++){
    const int xs = x0 + w*16 + kb*4 + rg;
    if (xs < 500){
      const size_t obase = (((size_t)(b*Hout + yo))*500 + xs)*64;
      #pragma unroll
      for (int nf = 0; nf < 4; nf++){
        const int oc = nf*16 + lr;
        const float bv = bias[oc];
        const float p0 = geluf(acc0[nf][rg] + bv);
        const float p1 = geluf(acc1[nf][rg] + bv);
        out[obase + oc] = __float2bfloat16(fmaxf(p0, p1));
      }
    }
  }
}

// ---------------- tokens: NHWC conv4 out -> tk[b*T+t][ci*12+yo] ----------------
__global__ __launch_bounds__(256) void tokens_k(const bf16* __restrict__ n4, bf16* __restrict__ tk)
{
  const int idx = blockIdx.x*256 + threadIdx.x;
  if (idx >= B_*12*500*64) return;
  const int ci = idx & 63;
  const int t  = (idx >> 6) % 500;
  const int yo = (idx >> 6) / 500 % 12;
  const int b  = idx / (64*500*12);
  tk[((size_t)(b*500 + t))*768 + ci*12 + yo] = n4[idx];
}

// ---------------- er fp32 -> bf16 ----------------
__global__ __launch_bounds__(256) void er2bf_k(const float* __restrict__ er, bf16* __restrict__ out)
{
  const int idx = blockIdx.x*256 + threadIdx.x;
  if (idx < T_*DH_) out[idx] = __float2bfloat16(er[idx]);
}

// ---------------- fp32 -> bf16 bulk cast (vectorized) ----------------
__global__ __launch_bounds__(256) void f2bf_k(const float* __restrict__ x, bf16* __restrict__ out, int n4)
{
  const int idx = blockIdx.x*256 + threadIdx.x;
  if (idx >= n4) return;
  const float4 v = *reinterpret_cast<const float4*>(x + idx*4);
  ushort4 u;
  u.x = __bfloat16_as_ushort(__float2bfloat16(v.x));
  u.y = __bfloat16_as_ushort(__float2bfloat16(v.y));
  u.z = __bfloat16_as_ushort(__float2bfloat16(v.z));
  u.w = __bfloat16_as_ushort(__float2bfloat16(v.w));
  *reinterpret_cast<ushort4*>(out + idx*4) = u;
}

// ---------------- bias pack: [bq|bk|bv] -> out[2304] fp32 ----------------
__global__ __launch_bounds__(256) void pack3_k(const float* __restrict__ a,
    const float* __restrict__ b, const float* __restrict__ c, float* __restrict__ out)
{
  const int i = blockIdx.x*256 + threadIdx.x;
  if (i >= QKVS) return;
  out[i] = (i < 768) ? a[i] : ((i < 1536) ? b[i - 768] : c[i - 1536]);
}

// ---------------- weight transpose+convert: fp32 [K][N] -> bf16 [N][K] ----------------
__global__ __launch_bounds__(256) void transpose_w(const float* __restrict__ W,
    bf16* __restrict__ out, int K, int N)
{
  __shared__ float tile[32][33];
  const int gk = blockIdx.y*32, gn = blockIdx.x*32;
  const int tr = threadIdx.x >> 5, tc = threadIdx.x & 31;
  #pragma unroll
  for (int i = 0; i < 4; i++)
    tile[tr + i*8][tc] = W[(size_t)(gk + tr + i*8)*N + gn + tc];
  __syncthreads();
  #pragma unroll
  for (int i = 0; i < 4; i++)
    out[(size_t)(gn + tr + i*8)*K + gk + tc] = __float2bfloat16(tile[tc][tr + i*8]);
}

// ---------------- MFMA GEMM with async global->LDS staging (m97 structure) ----------------
// C = act(A[MxK](bf16) @ Bt[NxK]^T(bf16) + bias) (+resid)
template<int ACT, int RESID, int BF16OUT>
__global__ __launch_bounds__(256) void mfma_gemm_k(const bf16* __restrict__ A,
    const bf16* __restrict__ Bt, const float* __restrict__ bias,
    const float* __restrict__ resid, void* __restrict__ Cout, int M, int N, int K)
{
  __shared__ uint4 Alds[512];
  __shared__ uint4 Blds[512];

  const int tid = threadIdx.x;
  const int wid = tid >> 6, lane = tid & 63;
  const int wr = wid >> 1, wc = wid & 1;
  const int bm = blockIdx.y*128, bn = blockIdx.x*128;

  const int g0 = tid >> 7;          // 0..1 (second chunk at g0+2)
  const int r0 = tid & 127;
  const int arow = min(bm + r0, M-1);
  const int brow = min(bn + r0, N-1);
  const int lg = lane >> 4, lr = lane & 15;

  const bf16* aptr = A  + (size_t)arow*K + g0*8;
  const bf16* bptr = Bt + (size_t)brow*K + g0*8;
  uint4* adst0 = &Alds[g0*128 + r0];
  uint4* adst1 = &Alds[(g0+2)*128 + r0];
  uint4* bdst0 = &Blds[g0*128 + r0];
  uint4* bdst1 = &Blds[(g0+2)*128 + r0];

  f32x4 acc[4][4];
  #pragma unroll
  for (int i = 0; i < 4; i++)
    #pragma unroll
    for (int j = 0; j < 4; j++)
      acc[i][j] = (f32x4){0.f,0.f,0.f,0.f};

  for (int k0 = 0; k0 < K; k0 += 32){
    __syncthreads();                       // previous iteration's ds_reads done
    gload_lds16(aptr + k0,      adst0);    // async 16B/lane direct to LDS
    gload_lds16(aptr + k0 + 16, adst1);
    gload_lds16(bptr + k0,      bdst0);
    gload_lds16(bptr + k0 + 16, bdst1);
    __syncthreads();                       // vmcnt drain: tiles resident

    bf16x8 af[4], bfr[4];
    #pragma unroll
    for (int mf = 0; mf < 4; mf++)
      af[mf] = *reinterpret_cast<const bf16x8*>(&Alds[lg*128 + wr*64 + mf*16 + lr]);
    #pragma unroll
    for (int nf = 0; nf < 4; nf++)
      bfr[nf] = *reinterpret_cast<const bf16x8*>(&Blds[lg*128 + wc*64 + nf*16 + lr]);

    #pragma unroll
    for (int mf = 0; mf < 4; mf++)
      #pragma unroll
      for (int nf = 0; nf < 4; nf++)
        acc[mf][nf] = __builtin_amdgcn_mfma_f32_16x16x32_bf16(af[mf], bfr[nf], acc[mf][nf], 0, 0, 0);
  }

  #pragma unroll
  for (int mf = 0; mf < 4; mf++){
    #pragma unroll
    for (int rg = 0; rg < 4; rg++){
      const int row = bm + wr*64 + mf*16 + (lane>>4)*4 + rg;
      if (row >= M) continue;
      #pragma unroll
      for (int nf = 0; nf < 4; nf++){
        const int col = bn + wc*64 + nf*16 + (lane&15);
        if (col >= N) continue;
        float v = acc[mf][nf][rg] + bias[col];
        if (ACT == 1) v = geluf(v);
        if (RESID)    v += resid[(size_t)row*N + col];
        if (BF16OUT)  reinterpret_cast<bf16*>(Cout)[(size_t)row*N + col] = __float2bfloat16(v);
        else          reinterpret_cast<float*>(Cout)[(size_t)row*N + col] = v;
      }
    }
  }
}

// ---------------- LayerNorm over D=768: fp32 in -> bf16 out ----------------
__global__ __launch_bounds__(256) void layernorm_k(const float* __restrict__ x,
    const float* __restrict__ g, const float* __restrict__ bb, bf16* __restrict__ out)
{
  const int row = blockIdx.x;
  const float* xr = x + (size_t)row*D_;
  const int tid = threadIdx.x;
  const float v0 = xr[tid], v1 = xr[tid+256], v2 = xr[tid+512];

  float s = v0 + v1 + v2;
  #pragma unroll
  for (int o = 32; o > 0; o >>= 1) s += __shfl_xor(s, o);
  __shared__ float sm[4];
  const int wid = tid >> 6, lane = tid & 63;
  if (lane == 0) sm[wid] = s;
  __syncthreads();
  const float mean = (sm[0]+sm[1]+sm[2]+sm[3]) * (1.f/768.f);
  __syncthreads();

  const float d0 = v0-mean, d1 = v1-mean, d2 = v2-mean;
  float ss = d0*d0 + d1*d1 + d2*d2;
  #pragma unroll
  for (int o = 32; o > 0; o >>= 1) ss += __shfl_xor(ss, o);
  if (lane == 0) sm[wid] = ss;
  __syncthreads();
  const float var = (sm[0]+sm[1]+sm[2]+sm[3]) * (1.f/768.f);
  const float inv = rsqrtf(var + 1e-5f);

  bf16* orow = out + (size_t)row*D_;
  orow[tid]     = __float2bfloat16(d0*inv*g[tid]     + bb[tid]);
  orow[tid+256] = __float2bfloat16(d1*inv*g[tid+256] + bb[tid+256]);
  orow[tid+512] = __float2bfloat16(d2*inv*g[tid+512] + bb[tid+512]);
}

// ---------------- flash attention on packed QKV [8000][2304]: MFMA QK^T + split-K + bf16 qer ----------------
// srel[q,k]: k<=q -> qer[q-q0][499-(q-k)] ; k==q+1 -> 0 ; k>q+1 -> qer[q-q0+1][k-q-2]
__global__ __launch_bounds__(256) void flash_attn_k(const bf16* __restrict__ qkv,
    const bf16* __restrict__ erb, bf16* __restrict__ ob)
{
  const int b = blockIdx.y / NH_, h = blockIdx.y % NH_;
  const int q0 = blockIdx.x * 16;
  const int tid = threadIdx.x;
  const int w = tid >> 6, lane = tid & 63;
  const int lr = lane & 15, lg = lane >> 4;

  __shared__ unsigned short qer_l[17][520];   // 17.7 KB bf16 qer
  __shared__ float vs[64][68];                // 17.4 KB V superblock
  __shared__ float S_lds[4][16][19];
  __shared__ float tmax_lds[4][16];
  __shared__ float mfin[4][16], lfin[4][16];
  float* mrg = &vs[0][0];                     // merge overlay, stride 68 (bank-safe)

  const bf16* qbase = qkv + h*DH_;            // + row*QKVS
  const bf16* kbase = qkv + 768 + h*DH_;
  const bf16* vbase = qkv + 1536 + h*DH_;

  // ---- Q fragment (rows q0..q0+15), reused for qer and QK^T ----
  int qq0 = q0 + lr;      if (qq0 > 499) qq0 = 499;
  bf16x8 qf[2];
  #pragma unroll
  for (int h2 = 0; h2 < 2; h2++)
    qf[h2] = *reinterpret_cast<const bf16x8*>(qbase + (size_t)(b*T_ + qq0)*QKVS + h2*32 + lg*8);

  // ---- qer[r][c] = Q[q0+r]·er[c], rows 0..16, via MFMA ----
  {
    int qq1 = q0 + 16 + lr; if (qq1 > 499) qq1 = 499;
    bf16x8 a1f[2];
    #pragma unroll
    for (int h2 = 0; h2 < 2; h2++)
      a1f[h2] = *reinterpret_cast<const bf16x8*>(qbase + (size_t)(b*T_ + qq1)*QKVS + h2*32 + lg*8);
    for (int ct = w; ct < 32; ct += 4){
      const int c0 = ct*16;
      int cc = c0 + lr; if (cc > 499) cc = 499;
      bf16x8 bw[2];
      #pragma unroll
      for (int h2 = 0; h2 < 2; h2++)
        bw[h2] = *reinterpret_cast<const bf16x8*>(erb + (size_t)cc*DH_ + h2*32 + lg*8);
      f32x4 c0a = (f32x4){0,0,0,0}, c1a = (f32x4){0,0,0,0};
      c0a = __builtin_amdgcn_mfma_f32_16x16x32_bf16(qf[0],  bw[0], c0a, 0, 0, 0);
      c0a = __builtin_amdgcn_mfma_f32_16x16x32_bf16(qf[1],  bw[1], c0a, 0, 0, 0);
      c1a = __builtin_amdgcn_mfma_f32_16x16x32_bf16(a1f[0], bw[0], c1a, 0, 0, 0);
      c1a = __builtin_amdgcn_mfma_f32_16x16x32_bf16(a1f[1], bw[1], c1a, 0, 0, 0);
      #pragma unroll
      for (int rg = 0; rg < 4; rg++)
        qer_l[lg*4 + rg][c0 + lr] = __bfloat16_as_ushort(__float2bfloat16(c0a[rg]));
      if (lg == 0) qer_l[16][c0 + lr] = __bfloat16_as_ushort(__float2bfloat16(c1a[0]));
    }
  }

  // ---- initial V stage: superblock 0 ----
  const int skr = tid >> 2;
  const int sc  = (tid & 3) * 16;
  {
    const int krow = min(skr, 499);
    const bf16* vp = vbase + (size_t)(b*T_ + krow)*QKVS + sc;
    const ushort4 u0 = *reinterpret_cast<const ushort4*>(vp);
    const ushort4 u1 = *reinterpret_cast<const ushort4*>(vp + 4);
    const ushort4 u2 = *reinterpret_cast<const ushort4*>(vp + 8);
    const ushort4 u3 = *reinterpret_cast<const ushort4*>(vp + 12);
    float* d = &vs[skr][sc];
    d[0]=bfu2f(u0.x); d[1]=bfu2f(u0.y); d[2]=bfu2f(u0.z); d[3]=bfu2f(u0.w);
    d[4]=bfu2f(u1.x); d[5]=bfu2f(u1.y); d[6]=bfu2f(u1.z); d[7]=bfu2f(u1.w);
    d[8]=bfu2f(u2.x); d[9]=bfu2f(u2.y); d[10]=bfu2f(u2.z); d[11]=bfu2f(u2.w);
    d[12]=bfu2f(u3.x); d[13]=bfu2f(u3.y); d[14]=bfu2f(u3.z); d[15]=bfu2f(u3.w);
  }
  __syncthreads();

  float m = -3.0e38f, l = 0.f;
  float oacc[16];
  #pragma unroll
  for (int j = 0; j < 16; j++) oacc[j] = 0.f;

  for (int sb = 0; sb < 8; sb++){
    const int K0 = sb*64;
    const bool pf = (sb < 7);
    ushort4 p0, p1, p2, p3;
    if (pf){
      const int krow = min(K0 + 64 + skr, 499);
      const bf16* vp = vbase + (size_t)(b*T_ + krow)*QKVS + sc;
      p0 = *reinterpret_cast<const ushort4*>(vp);
      p1 = *reinterpret_cast<const ushort4*>(vp + 4);
      p2 = *reinterpret_cast<const ushort4*>(vp + 8);
      p3 = *reinterpret_cast<const ushort4*>(vp + 12);
    }

    // ---- S-tile via MFMA: wave w handles k-tile k0 = K0 + w*16 ----
    const int k0 = K0 + w*16;
    int kk = k0 + lr; if (kk > 499) kk = 499;
    bf16x8 kf[2];
    #pragma unroll
    for (int h2 = 0; h2 < 2; h2++)
      kf[h2] = *reinterpret_cast<const bf16x8*>(kbase + (size_t)(b*T_ + kk)*QKVS + h2*32 + lg*8);
    f32x4 sacc = (f32x4){0,0,0,0};
    sacc = __builtin_amdgcn_mfma_f32_16x16x32_bf16(qf[0], kf[0], sacc, 0, 0, 0);
    sacc = __builtin_amdgcn_mfma_f32_16x16x32_bf16(qf[1], kf[1], sacc, 0, 0, 0);

    const int kcol = k0 + lr;
    float sv[4];
    #pragma unroll
    for (int rg = 0; rg < 4; rg++){
      const int r = lg*4 + rg;
      const int q = q0 + r;
      float d2 = 0.f;
      if (kcol != q + 1){
        const int eidx = (kcol <= q) ? (499 - q + kcol) : (kcol - q - 2);
        d2 = bfu2f(qer_l[(kcol <= q) ? r : r + 1][eidx]);
      }
      float s = (sacc[rg] + d2) * 0.125f;
      if (kcol >= 500) s = -3.0e38f;
      sv[rg] = s;
    }
    float tm[4];
    #pragma unroll
    for (int rg = 0; rg < 4; rg++){
      tm[rg] = sv[rg];
      #pragma unroll
      for (int o = 8; o > 0; o >>= 1) tm[rg] = fmaxf(tm[rg], __shfl_xor(tm[rg], o, 16));
    }
    #pragma unroll
    for (int rg = 0; rg < 4; rg++) S_lds[w][lg*4 + rg][lr] = sv[rg];
    if (lr == 0){
      #pragma unroll
      for (int rg = 0; rg < 4; rg++) tmax_lds[w][lg*4 + rg] = tm[rg];
    }

    // ---- PV: lane owns row q'=lr, d-range lg*16..+15 ----
    const float tmv = tmax_lds[w][lr];
    const float mn = fmaxf(m, tmv);
    const float corr = __expf(m - mn);
    m = mn;
    l *= corr;
    #pragma unroll
    for (int j = 0; j < 16; j++) oacc[j] *= corr;

    #pragma unroll
    for (int k2 = 0; k2 < 16; k2++){
      const float p = __expf(S_lds[w][lr][k2] - mn);
      l += p;
      const float* vrow = &vs[w*16 + k2][lg*16];
      const float4 va = *reinterpret_cast<const float4*>(vrow);
      const float4 vbv = *reinterpret_cast<const float4*>(vrow + 4);
      const float4 vc = *reinterpret_cast<const float4*>(vrow + 8);
      const float4 vd = *reinterpret_cast<const float4*>(vrow + 12);
      oacc[0]  = fmaf(p, va.x,  oacc[0]);  oacc[1]  = fmaf(p, va.y,  oacc[1]);
      oacc[2]  = fmaf(p, va.z,  oacc[2]);  oacc[3]  = fmaf(p, va.w,  oacc[3]);
      oacc[4]  = fmaf(p, vbv.x, oacc[4]);  oacc[5]  = fmaf(p, vbv.y, oacc[5]);
      oacc[6]  = fmaf(p, vbv.z, oacc[6]);  oacc[7]  = fmaf(p, vbv.w, oacc[7]);
      oacc[8]  = fmaf(p, vc.x,  oacc[8]);  oacc[9]  = fmaf(p, vc.y,  oacc[9]);
      oacc[10] = fmaf(p, vc.z,  oacc[10]); oacc[11] = fmaf(p, vc.w,  oacc[11]);
      oacc[12] = fmaf(p, vd.x,  oacc[12]); oacc[13] = fmaf(p, vd.y,  oacc[13]);
      oacc[14] = fmaf(p, vd.z,  oacc[14]); oacc[15] = fmaf(p, vd.w,  oacc[15]);
    }

    if (pf){
      __syncthreads();
      float* d = &vs[skr][sc];
      d[0]=bfu2f(p0.x); d[1]=bfu2f(p0.y); d[2]=bfu2f(p0.z); d[3]=bfu2f(p0.w);
      d[4]=bfu2f(p1.x); d[5]=bfu2f(p1.y); d[6]=bfu2f(p1.z); d[7]=bfu2f(p1.w);
      d[8]=bfu2f(p2.x); d[9]=bfu2f(p2.y); d[10]=bfu2f(p2.z); d[11]=bfu2f(p2.w);
      d[12]=bfu2f(p3.x); d[13]=bfu2f(p3.y); d[14]=bfu2f(p3.z); d[15]=bfu2f(p3.w);
      __syncthreads();
    }
  }

  // ---- split-K merge (stride 68 overlay: bank-safe) ----
  __syncthreads();
  #pragma unroll
  for (int j4 = 0; j4 < 4; j4++)
    *reinterpret_cast<float4*>(&mrg[(w*16 + lr)*68 + lg*16 + j4*4]) =
      make_float4(oacc[j4*4+0], oacc[j4*4+1], oacc[j4*4+2], oacc[j4*4+3]);
  if (lg == 0){ mfin[w][lr] = m; lfin[w][lr] = l; }
  __syncthreads();

  const int qp = tid & 15, dgj = tid >> 4;
  float M = fmaxf(fmaxf(mfin[0][qp], mfin[1][qp]), fmaxf(mfin[2][qp], mfin[3][qp]));
  float L = 0.f, o0 = 0.f, o1 = 0.f, o2 = 0.f, o3 = 0.f;
  #pragma unroll
  for (int w2 = 0; w2 < 4; w2++){
    const float e = __expf(mfin[w2][qp] - M);
    L += lfin[w2][qp] * e;
    const float* src = &mrg[(w2*16 + qp)*68 + dgj*4];
    o0 = fmaf(e, src[0], o0); o1 = fmaf(e, src[1], o1);
    o2 = fmaf(e, src[2], o2); o3 = fmaf(e, src[3], o3);
  }
  const int q = q0 + qp;
  if (q < T_){
    const float inv = 1.f / L;
    bf16* op = ob + ((size_t)(b*T_ + q))*D_ + h*DH_ + dgj*4;
    ushort4 u;
    u.x = __bfloat16_as_ushort(__float2bfloat16(o0*inv));
    u.y = __bfloat16_as_ushort(__float2bfloat16(o1*inv));
    u.z = __bfloat16_as_ushort(__float2bfloat16(o2*inv));
    u.w = __bfloat16_as_ushort(__float2bfloat16(o3*inv));
    *reinterpret_cast<ushort4*>(op) = u;
  }
}

// =====================================================================
extern "C" void kernel_launch(void* const* d_in, const int* in_sizes, int n_in,
                              void* d_out, int out_size, void* d_ws, size_t ws_size,
                              hipStream_t stream)
{
  const float* spec  = (const float*)d_in[0];
  const float* cw1 = (const float*)d_in[1];  const float* cb1 = (const float*)d_in[2];
  const float* cw2 = (const float*)d_in[3];  const float* cb2 = (const float*)d_in[4];
  const float* cw3 = (const float*)d_in[5];  const float* cb3 = (const float*)d_in[6];
  const float* cw4 = (const float*)d_in[7];  const float* cb4 = (const float*)d_in[8];
  const float* proj_w = (const float*)d_in[9];  const float* proj_b = (const float*)d_in[10];
  const float* ln1_g = (const float*)d_in[11];  const float* ln1_b = (const float*)d_in[12];
  const float* wq = (const float*)d_in[13];  const float* bq = (const float*)d_in[14];
  const float* wk = (const float*)d_in[15];  const float* bk = (const float*)d_in[16];
  const float* wv = (const float*)d_in[17];  const float* bv = (const float*)d_in[18];
  const float* wo = (const float*)d_in[19];  const float* bo = (const float*)d_in[20];
  const float* er = (const float*)d_in[21];
  const float* ln2_g = (const float*)d_in[22];  const float* ln2_b = (const float*)d_in[23];
  const float* w1 = (const float*)d_in[24];  const float* b1 = (const float*)d_in[25];
  const float* w2 = (const float*)d_in[26];  const float* b2 = (const float*)d_in[27];
  const float* dw = (const float*)d_in[28];  const float* db = (const float*)d_in[29];

  if (ws_size < 98304000ull) return;
  char* W = (char*)d_ws;
  bf16*  n1 = (bf16*) (W + 0);
  bf16*  n2 = (bf16*) (W + 49152000);
  bf16*  n3 = (bf16*) (W + 0);
  bf16*  n4 = (bf16*) (W + 24576000);
  bf16*  tk = (bf16*) (W + 49152000);
  float* xb = (float*)(W + 0);
  bf16*  xn = (bf16*) (W + 24576000);
  bf16*  qkv= (bf16*) (W + 36864000);    // packed [8000][2304], ends 73,728,000
  bf16*  ob = (bf16*) (W + 73728000);
  bf16*  hb = (bf16*) (W + 36864000);    // FFN hidden (qkv dead by then)
  bf16*  wt = (bf16*) (W + 86016000);    // up to 3.54 MB (QKV^T) / 4.72 MB (FFN)
  bf16*  erb= (bf16*) (W + 92274688);    // 64 KB
  float* qkvb=(float*)(W + 92340224);    // 9.2 KB packed bias
  bf16* cwt2 = (bf16*)d_out;
  bf16* cwt3 = (bf16*)((char*)d_out + 262144);
  bf16* cwt4 = (bf16*)((char*)d_out + 786432);

  // ---- CNN stack (NHWC, MFMA for conv2-4) ----
  conv_wt_k<32><<<(25*32*64 + 255)/256, 256, 0, stream>>>(cw2, cwt2);
  conv_wt_k<64><<<(25*64*64 + 255)/256, 256, 0, stream>>>(cw3, cwt3);
  conv_wt_k<64><<<(25*64*64 + 255)/256, 256, 0, stream>>>(cw4, cwt4);

  conv1_k<<<(B_*96*500 + 255)/256, 256, 0, stream>>>(spec, cw1, cb1, n1);
  conv_mfma_k<32><<<dim3(8, B_*48), 256, 0, stream>>>(n1, cwt2, cb2, n2, 96);
  conv_mfma_k<64><<<dim3(8, B_*24), 256, 0, stream>>>(n2, cwt3, cb3, n3, 48);
  conv_mfma_k<64><<<dim3(8, B_*12), 256, 0, stream>>>(n3, cwt4, cb4, n4, 24);

  tokens_k<<<(B_*12*500*64 + 255)/256, 256, 0, stream>>>(n4, tk);

  transpose_w<<<dim3(D_/32, D_/32), 256, 0, stream>>>(proj_w, wt, D_, D_);
  mfma_gemm_k<0,0,0><<<dim3(6,63), 256, 0, stream>>>(tk, wt, proj_b, nullptr, xb, 8000, D_, D_);

  // ---- transformer layers ----
  for (int l = 0; l < 3; l++){
    const size_t wOff = (size_t)l*D_*D_;
    layernorm_k<<<8000, 256, 0, stream>>>(xb, ln1_g + l*D_, ln1_b + l*D_, xn);

    // fused QKV: wt = [q^T | k^T | v^T] (2304 x 768), one GEMM into packed qkv
    transpose_w<<<dim3(D_/32, D_/32), 256, 0, stream>>>(wq + wOff, wt,            D_, D_);
    transpose_w<<<dim3(D_/32, D_/32), 256, 0, stream>>>(wk + wOff, wt + 589824,   D_, D_);
    transpose_w<<<dim3(D_/32, D_/32), 256, 0, stream>>>(wv + wOff, wt + 1179648,  D_, D_);
    pack3_k<<<(QKVS + 255)/256, 256, 0, stream>>>(bq + l*D_, bk + l*D_, bv + l*D_, qkvb);
    mfma_gemm_k<0,0,1><<<dim3(18,63), 256, 0, stream>>>(xn, wt, qkvb, nullptr, qkv, 8000, QKVS, D_);

    er2bf_k<<<(T_*DH_ + 255)/256, 256, 0, stream>>>(er + (size_t)l*T_*DH_, erb);
    flash_attn_k<<<dim3(32, B_*NH_), 256, 0, stream>>>(qkv, erb, ob);

    transpose_w<<<dim3(D_/32, D_/32), 256, 0, stream>>>(wo + wOff, wt, D_, D_);
    mfma_gemm_k<0,1,0><<<dim3(6,63), 256, 0, stream>>>(ob, wt, bo + l*D_, xb, xb, 8000, D_, D_);

    layernorm_k<<<8000, 256, 0, stream>>>(xb, ln2_g + l*D_, ln2_b + l*D_, xn);

    transpose_w<<<dim3(FFN_/32, D_/32), 256, 0, stream>>>(w1 + (size_t)l*D_*FFN_, wt, D_, FFN_);
    mfma_gemm_k<1,0,1><<<dim3(24,63), 256, 0, stream>>>(xn, wt, b1 + l*FFN_, nullptr, hb, 8000, FFN_, D_);
    transpose_w<<<dim3(D_/32, FFN_/32), 256, 0, stream>>>(w2 + (size_t)l*FFN_*D_, wt, FFN_, D_);
    mfma_gemm_k<0,1,0><<<dim3(6,63), 256, 0, stream>>>(hb, wt, b2 + l*D_, xb, xb, 8000, D_, FFN_);
  }

  // ---- deproj via MFMA -> fp32 output [8000, 192] ----
  f2bf_k<<<(8000*D_/4 + 255)/256, 256, 0, stream>>>(xb, xn, 8000*D_/4);
  transpose_w<<<dim3(192/32, D_/32), 256, 0, stream>>>(dw, wt, D_, 192);
  mfma_gemm_k<0,0,0><<<dim3(2,63), 256, 0, stream>>>(xn, wt, db, nullptr, d_out, 8000, 192, D_);
}

// Round 16
// 2233.340 us; speedup vs baseline: 1.0997x; 1.0997x over previous
//
#include <hip/hip_runtime.h>
#include <hip/hip_bf16.h>

typedef __hip_bfloat16 bf16;
typedef __attribute__((ext_vector_type(8))) short bf16x8;
typedef __attribute__((ext_vector_type(4))) float f32x4;

#define B_   16
#define T_   500
#define D_   768
#define NH_  12
#define DH_  64
#define FFN_ 3072
#define QKVS 2304

__device__ __forceinline__ float bfu2f(unsigned short u){ return __uint_as_float(((unsigned)u)<<16); }
__device__ __forceinline__ float geluf(float x){ return 0.5f*x*(1.0f + erff(x*0.70710678118654752f)); }

__device__ __forceinline__ float4 ld4f(const float* p){ return *reinterpret_cast<const float4*>(p); }
__device__ __forceinline__ float4 ld4f(const bf16* p){
  ushort4 u = *reinterpret_cast<const ushort4*>(p);
  return make_float4(bfu2f(u.x), bfu2f(u.y), bfu2f(u.z), bfu2f(u.w));
}

// async global->LDS, 16 bytes per lane (dst must be wave-uniform base + lane*16)
__device__ __forceinline__ void gload_lds16(const bf16* g, uint4* l){
  __builtin_amdgcn_global_load_lds(
      (const __attribute__((address_space(1))) void*)g,
      (__attribute__((address_space(3))) void*)l, 16, 0, 0);
}

// ---------------- conv1: Cin=1, 32 oc per thread, writes NHWC [b][96][500][32] ----------------
__global__ __launch_bounds__(256) void conv1_k(const float* __restrict__ spec,
    const float* __restrict__ w, const float* __restrict__ bias, bf16* __restrict__ out)
{
  const int pos = blockIdx.x*256 + threadIdx.x;
  if (pos >= B_*96*500) return;
  const int x  = pos % 500;
  const int yo = (pos/500) % 96;
  const int b  = pos/(500*96);
  const float* ip = spec + (size_t)b*192*500;

  float v[6][5];
  #pragma unroll
  for (int r = 0; r < 6; r++){
    const int yy = 2*yo - 2 + r;
    const bool vy = (yy >= 0) && (yy < 192);
    const float* rp = ip + (size_t)(vy ? yy : 0)*500;
    #pragma unroll
    for (int c = 0; c < 5; c++){
      const int xx = x - 2 + c;
      v[r][c] = (vy && xx >= 0 && xx < 500) ? rp[xx] : 0.f;
    }
  }

  const size_t obase = (((size_t)(b*96 + yo))*500 + x)*32;
  #pragma unroll
  for (int oc = 0; oc < 32; oc++){
    float a0 = bias[oc], a1 = bias[oc];
    #pragma unroll
    for (int r = 0; r < 5; r++)
      #pragma unroll
      for (int c = 0; c < 5; c++){
        const float wv = w[oc*25 + r*5 + c];
        a0 = fmaf(v[r][c],   wv, a0);
        a1 = fmaf(v[r+1][c], wv, a1);
      }
    out[obase + oc] = __float2bfloat16(fmaxf(geluf(a0), geluf(a1)));
  }
}

// ---------------- conv weight repack: OIHW fp32 -> bf16 [tap][cg][nf][lane][8] ----------------
template<int CIN>
__global__ __launch_bounds__(256) void conv_wt_k(const float* __restrict__ w, bf16* __restrict__ wt)
{
  const int e = blockIdx.x*256 + threadIdx.x;
  if (e >= 25*CIN*64) return;
  const int j    = e & 7;
  const int lane = (e >> 3) & 63;
  const int nf   = (e >> 9) & 3;
  const int t3   = e >> 11;
  const int cg   = t3 % (CIN/32);
  const int tap  = t3 / (CIN/32);
  const int oc = nf*16 + (lane & 15);
  const int ci = cg*32 + (lane >> 4)*8 + j;
  wt[e] = __float2bfloat16(w[(size_t)(oc*CIN + ci)*25 + tap]);
}

// ---------------- MFMA conv + GELU + pool, NHWC, LDS-staged branch-free inner loop ----------------
template<int CIN>
__global__ __launch_bounds__(256) void conv_mfma_k(const bf16* __restrict__ in,
    const bf16* __restrict__ wt, const float* __restrict__ bias,
    bf16* __restrict__ out, int Hin)
{
  constexpr int KB   = CIN/8;
  constexpr int ROWB = 68*CIN*2;
  __shared__ uint4 ldsu[6*68*CIN/8];
  char* lds = (char*)ldsu;

  const int Hout = Hin >> 1;
  const int x0 = blockIdx.x * 64;
  const int yo = blockIdx.y % Hout;
  const int b  = blockIdx.y / Hout;
  const int tid = threadIdx.x, w = tid >> 6, lane = tid & 63;
  const int lr = lane & 15, kb = lane >> 4;

  for (int idx = tid; idx < 6*68*KB; idx += 256){
    const int kbb = idx % KB;
    const int xx  = (idx/KB) % 68;
    const int r   = idx/(KB*68);
    const int yy = 2*yo + r - 2;
    const int xg = x0 + xx - 2;
    uint4 v = make_uint4(0,0,0,0);
    if (yy >= 0 && yy < Hin && xg >= 0 && xg < 500)
      v = *reinterpret_cast<const uint4*>(in + (((size_t)(b*Hin + yy))*500 + xg)*CIN + kbb*8);
    int off = r*ROWB + xx*(CIN*2) + kbb*16;
    off ^= (xx & 7) << 4;
    *reinterpret_cast<uint4*>(lds + off) = v;
  }
  __syncthreads();

  f32x4 acc0[4], acc1[4];
  #pragma unroll
  for (int nf = 0; nf < 4; nf++){ acc0[nf] = (f32x4){0,0,0,0}; acc1[nf] = (f32x4){0,0,0,0}; }

  const int xl = w*16 + lr;
  #pragma unroll
  for (int ky = 0; ky < 5; ky++){
    #pragma unroll
    for (int kx = 0; kx < 5; kx++){
      const int xx = xl + kx;
      const int tap = ky*5 + kx;
      #pragma unroll
      for (int cg = 0; cg < CIN/32; cg++){
        int aoff = ky*ROWB + xx*(CIN*2) + (cg*32 + kb*8)*2;
        aoff ^= (xx & 7) << 4;
        const bf16x8 a0 = *reinterpret_cast<const bf16x8*>(lds + aoff);
        const bf16x8 a1 = *reinterpret_cast<const bf16x8*>(lds + aoff + ROWB);
        const bf16* bp = wt + ((size_t)((tap*(CIN/32) + cg)*4)*64 + lane)*8;
        #pragma unroll
        for (int nf = 0; nf < 4; nf++){
          const bf16x8 bf_ = *reinterpret_cast<const bf16x8*>(bp + nf*512);
          acc0[nf] = __builtin_amdgcn_mfma_f32_16x16x32_bf16(a0, bf_, acc0[nf], 0, 0, 0);
          acc1[nf] = __builtin_amdgcn_mfma_f32_16x16x32_bf16(a1, bf_, acc1[nf], 0, 0, 0);
        }
      }
    }
  }

  #pragma unroll
  for (int rg = 0; rg < 4; rg++){
    const int xs = x0 + w*16 + kb*4 + rg;
    if (xs < 500){
      const size_t obase = (((size_t)(b*Hout + yo))*500 + xs)*64;
      #pragma unroll
      for (int nf = 0; nf < 4; nf++){
        const int oc = nf*16 + lr;
        const float bv = bias[oc];
        const float p0 = geluf(acc0[nf][rg] + bv);
        const float p1 = geluf(acc1[nf][rg] + bv);
        out[obase + oc] = __float2bfloat16(fmaxf(p0, p1));
      }
    }
  }
}

// ---------------- tokens: NHWC conv4 out -> tk[b*T+t][ci*12+yo] ----------------
__global__ __launch_bounds__(256) void tokens_k(const bf16* __restrict__ n4, bf16* __restrict__ tk)
{
  const int idx = blockIdx.x*256 + threadIdx.x;
  if (idx >= B_*12*500*64) return;
  const int ci = idx & 63;
  const int t  = (idx >> 6) % 500;
  const int yo = (idx >> 6) / 500 % 12;
  const int b  = idx / (64*500*12);
  tk[((size_t)(b*500 + t))*768 + ci*12 + yo] = n4[idx];
}

// ---------------- er fp32 -> bf16 ----------------
__global__ __launch_bounds__(256) void er2bf_k(const float* __restrict__ er, bf16* __restrict__ out)
{
  const int idx = blockIdx.x*256 + threadIdx.x;
  if (idx < T_*DH_) out[idx] = __float2bfloat16(er[idx]);
}

// ---------------- fp32 -> bf16 bulk cast (vectorized) ----------------
__global__ __launch_bounds__(256) void f2bf_k(const float* __restrict__ x, bf16* __restrict__ out, int n4)
{
  const int idx = blockIdx.x*256 + threadIdx.x;
  if (idx >= n4) return;
  const float4 v = *reinterpret_cast<const float4*>(x + idx*4);
  ushort4 u;
  u.x = __bfloat16_as_ushort(__float2bfloat16(v.x));
  u.y = __bfloat16_as_ushort(__float2bfloat16(v.y));
  u.z = __bfloat16_as_ushort(__float2bfloat16(v.z));
  u.w = __bfloat16_as_ushort(__float2bfloat16(v.w));
  *reinterpret_cast<ushort4*>(out + idx*4) = u;
}

// ---------------- bias pack: [bq|bk|bv] -> out[2304] fp32 ----------------
__global__ __launch_bounds__(256) void pack3_k(const float* __restrict__ a,
    const float* __restrict__ b, const float* __restrict__ c, float* __restrict__ out)
{
  const int i = blockIdx.x*256 + threadIdx.x;
  if (i >= QKVS) return;
  out[i] = (i < 768) ? a[i] : ((i < 1536) ? b[i - 768] : c[i - 1536]);
}

// ---------------- weight transpose+convert: fp32 [K][N] -> bf16 [N][K] ----------------
__global__ __launch_bounds__(256) void transpose_w(const float* __restrict__ W,
    bf16* __restrict__ out, int K, int N)
{
  __shared__ float tile[32][33];
  const int gk = blockIdx.y*32, gn = blockIdx.x*32;
  const int tr = threadIdx.x >> 5, tc = threadIdx.x & 31;
  #pragma unroll
  for (int i = 0; i < 4; i++)
    tile[tr + i*8][tc] = W[(size_t)(gk + tr + i*8)*N + gn + tc];
  __syncthreads();
  #pragma unroll
  for (int i = 0; i < 4; i++)
    out[(size_t)(gn + tr + i*8)*K + gk + tc] = __float2bfloat16(tile[tc][tr + i*8]);
}

// ---------------- MFMA GEMM with async global->LDS staging ----------------
template<int ACT, int RESID, int BF16OUT>
__global__ __launch_bounds__(256) void mfma_gemm_k(const bf16* __restrict__ A,
    const bf16* __restrict__ Bt, const float* __restrict__ bias,
    const float* __restrict__ resid, void* __restrict__ Cout, int M, int N, int K)
{
  __shared__ uint4 Alds[512];
  __shared__ uint4 Blds[512];

  const int tid = threadIdx.x;
  const int wid = tid >> 6, lane = tid & 63;
  const int wr = wid >> 1, wc = wid & 1;
  const int bm = blockIdx.y*128, bn = blockIdx.x*128;

  const int g0 = tid >> 7;
  const int r0 = tid & 127;
  const int arow = min(bm + r0, M-1);
  const int brow = min(bn + r0, N-1);
  const int lg = lane >> 4, lr = lane & 15;

  const bf16* aptr = A  + (size_t)arow*K + g0*8;
  const bf16* bptr = Bt + (size_t)brow*K + g0*8;
  uint4* adst0 = &Alds[g0*128 + r0];
  uint4* adst1 = &Alds[(g0+2)*128 + r0];
  uint4* bdst0 = &Blds[g0*128 + r0];
  uint4* bdst1 = &Blds[(g0+2)*128 + r0];

  f32x4 acc[4][4];
  #pragma unroll
  for (int i = 0; i < 4; i++)
    #pragma unroll
    for (int j = 0; j < 4; j++)
      acc[i][j] = (f32x4){0.f,0.f,0.f,0.f};

  for (int k0 = 0; k0 < K; k0 += 32){
    __syncthreads();
    gload_lds16(aptr + k0,      adst0);
    gload_lds16(aptr + k0 + 16, adst1);
    gload_lds16(bptr + k0,      bdst0);
    gload_lds16(bptr + k0 + 16, bdst1);
    __syncthreads();

    bf16x8 af[4], bfr[4];
    #pragma unroll
    for (int mf = 0; mf < 4; mf++)
      af[mf] = *reinterpret_cast<const bf16x8*>(&Alds[lg*128 + wr*64 + mf*16 + lr]);
    #pragma unroll
    for (int nf = 0; nf < 4; nf++)
      bfr[nf] = *reinterpret_cast<const bf16x8*>(&Blds[lg*128 + wc*64 + nf*16 + lr]);

    #pragma unroll
    for (int mf = 0; mf < 4; mf++)
      #pragma unroll
      for (int nf = 0; nf < 4; nf++)
        acc[mf][nf] = __builtin_amdgcn_mfma_f32_16x16x32_bf16(af[mf], bfr[nf], acc[mf][nf], 0, 0, 0);
  }

  #pragma unroll
  for (int mf = 0; mf < 4; mf++){
    #pragma unroll
    for (int rg = 0; rg < 4; rg++){
      const int row = bm + wr*64 + mf*16 + (lane>>4)*4 + rg;
      if (row >= M) continue;
      #pragma unroll
      for (int nf = 0; nf < 4; nf++){
        const int col = bn + wc*64 + nf*16 + (lane&15);
        if (col >= N) continue;
        float v = acc[mf][nf][rg] + bias[col];
        if (ACT == 1) v = geluf(v);
        if (RESID)    v += resid[(size_t)row*N + col];
        if (BF16OUT)  reinterpret_cast<bf16*>(Cout)[(size_t)row*N + col] = __float2bfloat16(v);
        else          reinterpret_cast<float*>(Cout)[(size_t)row*N + col] = v;
      }
    }
  }
}

// ---------------- LayerNorm over D=768: fp32 in -> bf16 out ----------------
__global__ __launch_bounds__(256) void layernorm_k(const float* __restrict__ x,
    const float* __restrict__ g, const float* __restrict__ bb, bf16* __restrict__ out)
{
  const int row = blockIdx.x;
  const float* xr = x + (size_t)row*D_;
  const int tid = threadIdx.x;
  const float v0 = xr[tid], v1 = xr[tid+256], v2 = xr[tid+512];

  float s = v0 + v1 + v2;
  #pragma unroll
  for (int o = 32; o > 0; o >>= 1) s += __shfl_xor(s, o);
  __shared__ float sm[4];
  const int wid = tid >> 6, lane = tid & 63;
  if (lane == 0) sm[wid] = s;
  __syncthreads();
  const float mean = (sm[0]+sm[1]+sm[2]+sm[3]) * (1.f/768.f);
  __syncthreads();

  const float d0 = v0-mean, d1 = v1-mean, d2 = v2-mean;
  float ss = d0*d0 + d1*d1 + d2*d2;
  #pragma unroll
  for (int o = 32; o > 0; o >>= 1) ss += __shfl_xor(ss, o);
  if (lane == 0) sm[wid] = ss;
  __syncthreads();
  const float var = (sm[0]+sm[1]+sm[2]+sm[3]) * (1.f/768.f);
  const float inv = rsqrtf(var + 1e-5f);

  bf16* orow = out + (size_t)row*D_;
  orow[tid]     = __float2bfloat16(d0*inv*g[tid]     + bb[tid]);
  orow[tid+256] = __float2bfloat16(d1*inv*g[tid+256] + bb[tid+256]);
  orow[tid+512] = __float2bfloat16(d2*inv*g[tid+512] + bb[tid+512]);
}

// ---------------- flash attention: MFMA QK^T + MFMA PV (d-split), no split-K merge ----------------
// srel[q,k]: k<=q -> qer[q-q0][499-(q-k)] ; k==q+1 -> 0 ; k>q+1 -> qer[q-q0+1][k-q-2]
__global__ __launch_bounds__(256) void flash_attn_k(const bf16* __restrict__ qkv,
    const bf16* __restrict__ erb, bf16* __restrict__ ob)
{
  const int b = blockIdx.y / NH_, h = blockIdx.y % NH_;
  const int q0 = blockIdx.x * 16;
  const int tid = threadIdx.x;
  const int w = tid >> 6, lane = tid & 63;
  const int lr = lane & 15, lg = lane >> 4;

  __shared__ unsigned short qer_l[17][520];   // 17.7 KB bf16 qer
  __shared__ unsigned short vs_u[64][72];     // 9.2 KB V superblock (bf16)
  __shared__ float S_f[16][68];               // 4.3 KB S tile (16q x 64k), srel/scale/mask applied
  __shared__ float tmax_lds[4][16];

  const bf16* qbase = qkv + h*DH_;
  const bf16* kbase = qkv + 768 + h*DH_;
  const bf16* vbase = qkv + 1536 + h*DH_;

  // ---- Q fragment (rows q0..q0+15) ----
  int qq0 = q0 + lr; if (qq0 > 499) qq0 = 499;
  bf16x8 qf[2];
  #pragma unroll
  for (int h2 = 0; h2 < 2; h2++)
    qf[h2] = *reinterpret_cast<const bf16x8*>(qbase + (size_t)(b*T_ + qq0)*QKVS + h2*32 + lg*8);

  // ---- qer[r][c] = Q[q0+r]·er[c], rows 0..16, via MFMA ----
  {
    int qq1 = q0 + 16 + lr; if (qq1 > 499) qq1 = 499;
    bf16x8 a1f[2];
    #pragma unroll
    for (int h2 = 0; h2 < 2; h2++)
      a1f[h2] = *reinterpret_cast<const bf16x8*>(qbase + (size_t)(b*T_ + qq1)*QKVS + h2*32 + lg*8);
    for (int ct = w; ct < 32; ct += 4){
      const int c0 = ct*16;
      int cc = c0 + lr; if (cc > 499) cc = 499;
      bf16x8 bw[2];
      #pragma unroll
      for (int h2 = 0; h2 < 2; h2++)
        bw[h2] = *reinterpret_cast<const bf16x8*>(erb + (size_t)cc*DH_ + h2*32 + lg*8);
      f32x4 c0a = (f32x4){0,0,0,0}, c1a = (f32x4){0,0,0,0};
      c0a = __builtin_amdgcn_mfma_f32_16x16x32_bf16(qf[0],  bw[0], c0a, 0, 0, 0);
      c0a = __builtin_amdgcn_mfma_f32_16x16x32_bf16(qf[1],  bw[1], c0a, 0, 0, 0);
      c1a = __builtin_amdgcn_mfma_f32_16x16x32_bf16(a1f[0], bw[0], c1a, 0, 0, 0);
      c1a = __builtin_amdgcn_mfma_f32_16x16x32_bf16(a1f[1], bw[1], c1a, 0, 0, 0);
      #pragma unroll
      for (int rg = 0; rg < 4; rg++)
        qer_l[lg*4 + rg][c0 + lr] = __bfloat16_as_ushort(__float2bfloat16(c0a[rg]));
      if (lg == 0) qer_l[16][c0 + lr] = __bfloat16_as_ushort(__float2bfloat16(c1a[0]));
    }
  }

  // ---- initial V stage: superblock 0 (bf16, direct copy) ----
  const int skr = tid >> 2;            // 0..63
  const int sc  = (tid & 3) * 16;      // 0,16,32,48
  {
    const int krow = min(skr, 499);
    const bf16* vp = vbase + (size_t)(b*T_ + krow)*QKVS + sc;
    const uint4 u01 = *reinterpret_cast<const uint4*>(vp);
    const uint4 u23 = *reinterpret_cast<const uint4*>(vp + 8);
    *reinterpret_cast<uint4*>(&vs_u[skr][sc])     = u01;
    *reinterpret_cast<uint4*>(&vs_u[skr][sc + 8]) = u23;
  }
  __syncthreads();

  float m_q = -3.0e38f, l_q = 0.f;     // per-lane stats for q = q0 + lr
  f32x4 acc = (f32x4){0.f,0.f,0.f,0.f};// C: row q'=lg*4+rg, col d = w*16 + lr

  for (int sb = 0; sb < 8; sb++){
    const int K0 = sb*64;
    const bool pf = (sb < 7);
    uint4 pva, pvb;
    if (pf){
      const int krow = min(K0 + 64 + skr, 499);
      const bf16* vp = vbase + (size_t)(b*T_ + krow)*QKVS + sc;
      pva = *reinterpret_cast<const uint4*>(vp);
      pvb = *reinterpret_cast<const uint4*>(vp + 8);
    }

    // ---- QK^T: wave w computes S for k-tile K0 + w*16 ----
    const int k0 = K0 + w*16;
    int kk = k0 + lr; if (kk > 499) kk = 499;
    bf16x8 kf[2];
    #pragma unroll
    for (int h2 = 0; h2 < 2; h2++)
      kf[h2] = *reinterpret_cast<const bf16x8*>(kbase + (size_t)(b*T_ + kk)*QKVS + h2*32 + lg*8);
    f32x4 sacc = (f32x4){0,0,0,0};
    sacc = __builtin_amdgcn_mfma_f32_16x16x32_bf16(qf[0], kf[0], sacc, 0, 0, 0);
    sacc = __builtin_amdgcn_mfma_f32_16x16x32_bf16(qf[1], kf[1], sacc, 0, 0, 0);

    const int kcol = k0 + lr;
    float sv[4], tm[4];
    #pragma unroll
    for (int rg = 0; rg < 4; rg++){
      const int r = lg*4 + rg;
      const int q = q0 + r;
      float d2 = 0.f;
      if (kcol != q + 1){
        const int eidx = (kcol <= q) ? (499 - q + kcol) : (kcol - q - 2);
        d2 = bfu2f(qer_l[(kcol <= q) ? r : r + 1][eidx]);
      }
      float s = (sacc[rg] + d2) * 0.125f;
      if (kcol >= 500) s = -3.0e38f;
      sv[rg] = s;
      tm[rg] = s;
      #pragma unroll
      for (int o = 8; o > 0; o >>= 1) tm[rg] = fmaxf(tm[rg], __shfl_xor(tm[rg], o, 16));
    }
    #pragma unroll
    for (int rg = 0; rg < 4; rg++) S_f[lg*4 + rg][w*16 + lr] = sv[rg];
    if (lr == 0){
      #pragma unroll
      for (int rg = 0; rg < 4; rg++) tmax_lds[w][lg*4 + rg] = tm[rg];
    }
    __syncthreads();    // S + tmax visible to all waves; V(current) still valid

    // ---- per-lane stats for q = lr ----
    const float tg = fmaxf(fmaxf(tmax_lds[0][lr], tmax_lds[1][lr]),
                           fmaxf(tmax_lds[2][lr], tmax_lds[3][lr]));
    const float mn = fmaxf(m_q, tg);
    const float corr = __expf(m_q - mn);
    m_q = mn;

    // ---- P-fragments: row lr, k = hh*32 + lg*8 + j ; exp + pack bf16 ----
    float psum = 0.f;
    bf16x8 pfr[2];
    #pragma unroll
    for (int hh = 0; hh < 2; hh++){
      const float4 sA = *reinterpret_cast<const float4*>(&S_f[lr][hh*32 + lg*8]);
      const float4 sB = *reinterpret_cast<const float4*>(&S_f[lr][hh*32 + lg*8 + 4]);
      float p0 = __expf(sA.x - mn), p1 = __expf(sA.y - mn);
      float p2 = __expf(sA.z - mn), p3 = __expf(sA.w - mn);
      float p4 = __expf(sB.x - mn), p5 = __expf(sB.y - mn);
      float p6 = __expf(sB.z - mn), p7 = __expf(sB.w - mn);
      psum += ((p0+p1)+(p2+p3)) + ((p4+p5)+(p6+p7));
      bf16x8 pk;
      pk[0] = (short)__bfloat16_as_ushort(__float2bfloat16(p0));
      pk[1] = (short)__bfloat16_as_ushort(__float2bfloat16(p1));
      pk[2] = (short)__bfloat16_as_ushort(__float2bfloat16(p2));
      pk[3] = (short)__bfloat16_as_ushort(__float2bfloat16(p3));
      pk[4] = (short)__bfloat16_as_ushort(__float2bfloat16(p4));
      pk[5] = (short)__bfloat16_as_ushort(__float2bfloat16(p5));
      pk[6] = (short)__bfloat16_as_ushort(__float2bfloat16(p6));
      pk[7] = (short)__bfloat16_as_ushort(__float2bfloat16(p7));
      pfr[hh] = pk;
    }
    psum += __shfl_xor(psum, 16);
    psum += __shfl_xor(psum, 32);
    l_q = l_q*corr + psum;

    // ---- rescale acc rows by their corr (row q' = lg*4+rg) ----
    #pragma unroll
    for (int rg = 0; rg < 4; rg++){
      const float cr = __shfl(corr, lg*4 + rg, 16);
      acc[rg] *= cr;
    }

    // ---- PV: acc += P(16q x 32k) x V(32k x 16d), d-block = w*16..+15, two K=32 MFMAs ----
    #pragma unroll
    for (int hh = 0; hh < 2; hh++){
      bf16x8 vf;
      #pragma unroll
      for (int j = 0; j < 8; j++)
        vf[j] = (short)vs_u[hh*32 + lg*8 + j][w*16 + lr];
      acc = __builtin_amdgcn_mfma_f32_16x16x32_bf16(pfr[hh], vf, acc, 0, 0, 0);
    }

    __syncthreads();    // all S/V reads for sb done
    if (pf){
      *reinterpret_cast<uint4*>(&vs_u[skr][sc])     = pva;
      *reinterpret_cast<uint4*>(&vs_u[skr][sc + 8]) = pvb;
    }
    // next iteration's S writes happen pre-barrier1(next); V writes above are
    // separated from next readers by barrier1(next).
  }

  // ---- output: row q' = lg*4+rg, col d = w*16 + lr ----
  #pragma unroll
  for (int rg = 0; rg < 4; rg++){
    const int qp = lg*4 + rg;
    const int q = q0 + qp;
    if (q < T_){
      const float lrow = __shfl(l_q, qp, 16);
      ob[((size_t)(b*T_ + q))*D_ + h*DH_ + w*16 + lr] = __float2bfloat16(acc[rg] / lrow);
    }
  }
}

// =====================================================================
extern "C" void kernel_launch(void* const* d_in, const int* in_sizes, int n_in,
                              void* d_out, int out_size, void* d_ws, size_t ws_size,
                              hipStream_t stream)
{
  const float* spec  = (const float*)d_in[0];
  const float* cw1 = (const float*)d_in[1];  const float* cb1 = (const float*)d_in[2];
  const float* cw2 = (const float*)d_in[3];  const float* cb2 = (const float*)d_in[4];
  const float* cw3 = (const float*)d_in[5];  const float* cb3 = (const float*)d_in[6];
  const float* cw4 = (const float*)d_in[7];  const float* cb4 = (const float*)d_in[8];
  const float* proj_w = (const float*)d_in[9];  const float* proj_b = (const float*)d_in[10];
  const float* ln1_g = (const float*)d_in[11];  const float* ln1_b = (const float*)d_in[12];
  const float* wq = (const float*)d_in[13];  const float* bq = (const float*)d_in[14];
  const float* wk = (const float*)d_in[15];  const float* bk = (const float*)d_in[16];
  const float* wv = (const float*)d_in[17];  const float* bv = (const float*)d_in[18];
  const float* wo = (const float*)d_in[19];  const float* bo = (const float*)d_in[20];
  const float* er = (const float*)d_in[21];
  const float* ln2_g = (const float*)d_in[22];  const float* ln2_b = (const float*)d_in[23];
  const float* w1 = (const float*)d_in[24];  const float* b1 = (const float*)d_in[25];
  const float* w2 = (const float*)d_in[26];  const float* b2 = (const float*)d_in[27];
  const float* dw = (const float*)d_in[28];  const float* db = (const float*)d_in[29];

  if (ws_size < 98304000ull) return;
  char* W = (char*)d_ws;
  bf16*  n1 = (bf16*) (W + 0);
  bf16*  n2 = (bf16*) (W + 49152000);
  bf16*  n3 = (bf16*) (W + 0);
  bf16*  n4 = (bf16*) (W + 24576000);
  bf16*  tk = (bf16*) (W + 49152000);
  float* xb = (float*)(W + 0);
  bf16*  xn = (bf16*) (W + 24576000);
  bf16*  qkv= (bf16*) (W + 36864000);
  bf16*  ob = (bf16*) (W + 73728000);
  bf16*  hb = (bf16*) (W + 36864000);
  bf16*  wt = (bf16*) (W + 86016000);
  bf16*  erb= (bf16*) (W + 92274688);
  float* qkvb=(float*)(W + 92340224);
  bf16* cwt2 = (bf16*)d_out;
  bf16* cwt3 = (bf16*)((char*)d_out + 262144);
  bf16* cwt4 = (bf16*)((char*)d_out + 786432);

  // ---- CNN stack (NHWC, MFMA for conv2-4) ----
  conv_wt_k<32><<<(25*32*64 + 255)/256, 256, 0, stream>>>(cw2, cwt2);
  conv_wt_k<64><<<(25*64*64 + 255)/256, 256, 0, stream>>>(cw3, cwt3);
  conv_wt_k<64><<<(25*64*64 + 255)/256, 256, 0, stream>>>(cw4, cwt4);

  conv1_k<<<(B_*96*500 + 255)/256, 256, 0, stream>>>(spec, cw1, cb1, n1);
  conv_mfma_k<32><<<dim3(8, B_*48), 256, 0, stream>>>(n1, cwt2, cb2, n2, 96);
  conv_mfma_k<64><<<dim3(8, B_*24), 256, 0, stream>>>(n2, cwt3, cb3, n3, 48);
  conv_mfma_k<64><<<dim3(8, B_*12), 256, 0, stream>>>(n3, cwt4, cb4, n4, 24);

  tokens_k<<<(B_*12*500*64 + 255)/256, 256, 0, stream>>>(n4, tk);

  transpose_w<<<dim3(D_/32, D_/32), 256, 0, stream>>>(proj_w, wt, D_, D_);
  mfma_gemm_k<0,0,0><<<dim3(6,63), 256, 0, stream>>>(tk, wt, proj_b, nullptr, xb, 8000, D_, D_);

  // ---- transformer layers ----
  for (int l = 0; l < 3; l++){
    const size_t wOff = (size_t)l*D_*D_;
    layernorm_k<<<8000, 256, 0, stream>>>(xb, ln1_g + l*D_, ln1_b + l*D_, xn);

    transpose_w<<<dim3(D_/32, D_/32), 256, 0, stream>>>(wq + wOff, wt,            D_, D_);
    transpose_w<<<dim3(D_/32, D_/32), 256, 0, stream>>>(wk + wOff, wt + 589824,   D_, D_);
    transpose_w<<<dim3(D_/32, D_/32), 256, 0, stream>>>(wv + wOff, wt + 1179648,  D_, D_);
    pack3_k<<<(QKVS + 255)/256, 256, 0, stream>>>(bq + l*D_, bk + l*D_, bv + l*D_, qkvb);
    mfma_gemm_k<0,0,1><<<dim3(18,63), 256, 0, stream>>>(xn, wt, qkvb, nullptr, qkv, 8000, QKVS, D_);

    er2bf_k<<<(T_*DH_ + 255)/256, 256, 0, stream>>>(er + (size_t)l*T_*DH_, erb);
    flash_attn_k<<<dim3(32, B_*NH_), 256, 0, stream>>>(qkv, erb, ob);

    transpose_w<<<dim3(D_/32, D_/32), 256, 0, stream>>>(wo + wOff, wt, D_, D_);
    mfma_gemm_k<0,1,0><<<dim3(6,63), 256, 0, stream>>>(ob, wt, bo + l*D_, xb, xb, 8000, D_, D_);

    layernorm_k<<<8000, 256, 0, stream>>>(xb, ln2_g + l*D_, ln2_b + l*D_, xn);

    transpose_w<<<dim3(FFN_/32, D_/32), 256, 0, stream>>>(w1 + (size_t)l*D_*FFN_, wt, D_, FFN_);
    mfma_gemm_k<1,0,1><<<dim3(24,63), 256, 0, stream>>>(xn, wt, b1 + l*FFN_, nullptr, hb, 8000, FFN_, D_);
    transpose_w<<<dim3(D_/32, FFN_/32), 256, 0, stream>>>(w2 + (size_t)l*FFN_*D_, wt, FFN_, D_);
    mfma_gemm_k<0,1,0><<<dim3(6,63), 256, 0, stream>>>(hb, wt, b2 + l*D_, xb, xb, 8000, D_, FFN_);
  }

  // ---- deproj via MFMA -> fp32 output [8000, 192] ----
  f2bf_k<<<(8000*D_/4 + 255)/256, 256, 0, stream>>>(xb, xn, 8000*D_/4);
  transpose_w<<<dim3(192/32, D_/32), 256, 0, stream>>>(dw, wt, D_, 192);
  mfma_gemm_k<0,0,0><<<dim3(2,63), 256, 0, stream>>>(xn, wt, db, nullptr, d_out, 8000, 192, D_);
}

// Round 17
// 2200.190 us; speedup vs baseline: 1.1163x; 1.0151x over previous
//
#include <hip/hip_runtime.h>
#include <hip/hip_bf16.h>

typedef __hip_bfloat16 bf16;
typedef __attribute__((ext_vector_type(8))) short bf16x8;
typedef __attribute__((ext_vector_type(4))) float f32x4;

#define B_   16
#define T_   500
#define D_   768
#define NH_  12
#define DH_  64
#define FFN_ 3072
#define QKVS 2304

__device__ __forceinline__ float bfu2f(unsigned short u){ return __uint_as_float(((unsigned)u)<<16); }
__device__ __forceinline__ float geluf(float x){ return 0.5f*x*(1.0f + erff(x*0.70710678118654752f)); }

__device__ __forceinline__ float4 ld4f(const float* p){ return *reinterpret_cast<const float4*>(p); }
__device__ __forceinline__ float4 ld4f(const bf16* p){
  ushort4 u = *reinterpret_cast<const ushort4*>(p);
  return make_float4(bfu2f(u.x), bfu2f(u.y), bfu2f(u.z), bfu2f(u.w));
}

// async global->LDS, 16 bytes per lane (dst must be wave-uniform base + lane*16)
__device__ __forceinline__ void gload_lds16(const bf16* g, uint4* l){
  __builtin_amdgcn_global_load_lds(
      (const __attribute__((address_space(1))) void*)g,
      (__attribute__((address_space(3))) void*)l, 16, 0, 0);
}

// ---------------- conv1: Cin=1, 32 oc per thread, vectorized 16B stores ----------------
__global__ __launch_bounds__(256) void conv1_k(const float* __restrict__ spec,
    const float* __restrict__ w, const float* __restrict__ bias, bf16* __restrict__ out)
{
  const int pos = blockIdx.x*256 + threadIdx.x;
  if (pos >= B_*96*500) return;
  const int x  = pos % 500;
  const int yo = (pos/500) % 96;
  const int b  = pos/(500*96);
  const float* ip = spec + (size_t)b*192*500;

  float v[6][5];
  #pragma unroll
  for (int r = 0; r < 6; r++){
    const int yy = 2*yo - 2 + r;
    const bool vy = (yy >= 0) && (yy < 192);
    const float* rp = ip + (size_t)(vy ? yy : 0)*500;
    #pragma unroll
    for (int c = 0; c < 5; c++){
      const int xx = x - 2 + c;
      v[r][c] = (vy && xx >= 0 && xx < 500) ? rp[xx] : 0.f;
    }
  }

  unsigned short us[32];
  #pragma unroll
  for (int oc = 0; oc < 32; oc++){
    float a0 = bias[oc], a1 = bias[oc];
    #pragma unroll
    for (int r = 0; r < 5; r++)
      #pragma unroll
      for (int c = 0; c < 5; c++){
        const float wv = w[oc*25 + r*5 + c];
        a0 = fmaf(v[r][c],   wv, a0);
        a1 = fmaf(v[r+1][c], wv, a1);
      }
    us[oc] = __bfloat16_as_ushort(__float2bfloat16(fmaxf(geluf(a0), geluf(a1))));
  }
  uint4* op = reinterpret_cast<uint4*>(out + (((size_t)(b*96 + yo))*500 + x)*32);
  op[0] = *reinterpret_cast<const uint4*>(&us[0]);
  op[1] = *reinterpret_cast<const uint4*>(&us[8]);
  op[2] = *reinterpret_cast<const uint4*>(&us[16]);
  op[3] = *reinterpret_cast<const uint4*>(&us[24]);
}

// ---------------- conv weight repack: OIHW fp32 -> bf16 [tap][cg][nf][lane][8] ----------------
template<int CIN>
__global__ __launch_bounds__(256) void conv_wt_k(const float* __restrict__ w, bf16* __restrict__ wt)
{
  const int e = blockIdx.x*256 + threadIdx.x;
  if (e >= 25*CIN*64) return;
  const int j    = e & 7;
  const int lane = (e >> 3) & 63;
  const int nf   = (e >> 9) & 3;
  const int t3   = e >> 11;
  const int cg   = t3 % (CIN/32);
  const int tap  = t3 / (CIN/32);
  const int oc = nf*16 + (lane & 15);
  const int ci = cg*32 + (lane >> 4)*8 + j;
  wt[e] = __float2bfloat16(w[(size_t)(oc*CIN + ci)*25 + tap]);
}

// ---------------- MFMA conv + GELU + pool, NHWC, LDS-staged branch-free inner loop ----------------
template<int CIN>
__global__ __launch_bounds__(256) void conv_mfma_k(const bf16* __restrict__ in,
    const bf16* __restrict__ wt, const float* __restrict__ bias,
    bf16* __restrict__ out, int Hin)
{
  constexpr int KB   = CIN/8;
  constexpr int ROWB = 68*CIN*2;
  __shared__ uint4 ldsu[6*68*CIN/8];
  char* lds = (char*)ldsu;

  const int Hout = Hin >> 1;
  const int x0 = blockIdx.x * 64;
  const int yo = blockIdx.y % Hout;
  const int b  = blockIdx.y / Hout;
  const int tid = threadIdx.x, w = tid >> 6, lane = tid & 63;
  const int lr = lane & 15, kb = lane >> 4;

  for (int idx = tid; idx < 6*68*KB; idx += 256){
    const int kbb = idx % KB;
    const int xx  = (idx/KB) % 68;
    const int r   = idx/(KB*68);
    const int yy = 2*yo + r - 2;
    const int xg = x0 + xx - 2;
    uint4 v = make_uint4(0,0,0,0);
    if (yy >= 0 && yy < Hin && xg >= 0 && xg < 500)
      v = *reinterpret_cast<const uint4*>(in + (((size_t)(b*Hin + yy))*500 + xg)*CIN + kbb*8);
    int off = r*ROWB + xx*(CIN*2) + kbb*16;
    off ^= (xx & 7) << 4;
    *reinterpret_cast<uint4*>(lds + off) = v;
  }
  __syncthreads();

  f32x4 acc0[4], acc1[4];
  #pragma unroll
  for (int nf = 0; nf < 4; nf++){ acc0[nf] = (f32x4){0,0,0,0}; acc1[nf] = (f32x4){0,0,0,0}; }

  const int xl = w*16 + lr;
  #pragma unroll
  for (int ky = 0; ky < 5; ky++){
    #pragma unroll
    for (int kx = 0; kx < 5; kx++){
      const int xx = xl + kx;
      const int tap = ky*5 + kx;
      #pragma unroll
      for (int cg = 0; cg < CIN/32; cg++){
        int aoff = ky*ROWB + xx*(CIN*2) + (cg*32 + kb*8)*2;
        aoff ^= (xx & 7) << 4;
        const bf16x8 a0 = *reinterpret_cast<const bf16x8*>(lds + aoff);
        const bf16x8 a1 = *reinterpret_cast<const bf16x8*>(lds + aoff + ROWB);
        const bf16* bp = wt + ((size_t)((tap*(CIN/32) + cg)*4)*64 + lane)*8;
        #pragma unroll
        for (int nf = 0; nf < 4; nf++){
          const bf16x8 bf_ = *reinterpret_cast<const bf16x8*>(bp + nf*512);
          acc0[nf] = __builtin_amdgcn_mfma_f32_16x16x32_bf16(a0, bf_, acc0[nf], 0, 0, 0);
          acc1[nf] = __builtin_amdgcn_mfma_f32_16x16x32_bf16(a1, bf_, acc1[nf], 0, 0, 0);
        }
      }
    }
  }

  #pragma unroll
  for (int rg = 0; rg < 4; rg++){
    const int xs = x0 + w*16 + kb*4 + rg;
    if (xs < 500){
      const size_t obase = (((size_t)(b*Hout + yo))*500 + xs)*64;
      #pragma unroll
      for (int nf = 0; nf < 4; nf++){
        const int oc = nf*16 + lr;
        const float bv = bias[oc];
        const float p0 = geluf(acc0[nf][rg] + bv);
        const float p1 = geluf(acc1[nf][rg] + bv);
        out[obase + oc] = __float2bfloat16(fmaxf(p0, p1));
      }
    }
  }
}

// ---------------- tokens: NHWC conv4 out -> tk[b*T+t][ci*12+yo] ----------------
__global__ __launch_bounds__(256) void tokens_k(const bf16* __restrict__ n4, bf16* __restrict__ tk)
{
  const int idx = blockIdx.x*256 + threadIdx.x;
  if (idx >= B_*12*500*64) return;
  const int ci = idx & 63;
  const int t  = (idx >> 6) % 500;
  const int yo = (idx >> 6) / 500 % 12;
  const int b  = idx / (64*500*12);
  tk[((size_t)(b*500 + t))*768 + ci*12 + yo] = n4[idx];
}

// ---------------- er fp32 -> bf16 ----------------
__global__ __launch_bounds__(256) void er2bf_k(const float* __restrict__ er, bf16* __restrict__ out)
{
  const int idx = blockIdx.x*256 + threadIdx.x;
  if (idx < T_*DH_) out[idx] = __float2bfloat16(er[idx]);
}

// ---------------- fp32 -> bf16 bulk cast (vectorized) ----------------
__global__ __launch_bounds__(256) void f2bf_k(const float* __restrict__ x, bf16* __restrict__ out, int n4)
{
  const int idx = blockIdx.x*256 + threadIdx.x;
  if (idx >= n4) return;
  const float4 v = *reinterpret_cast<const float4*>(x + idx*4);
  ushort4 u;
  u.x = __bfloat16_as_ushort(__float2bfloat16(v.x));
  u.y = __bfloat16_as_ushort(__float2bfloat16(v.y));
  u.z = __bfloat16_as_ushort(__float2bfloat16(v.z));
  u.w = __bfloat16_as_ushort(__float2bfloat16(v.w));
  *reinterpret_cast<ushort4*>(out + idx*4) = u;
}

// ---------------- bias pack: [bq|bk|bv] -> out[2304] fp32 ----------------
__global__ __launch_bounds__(256) void pack3_k(const float* __restrict__ a,
    const float* __restrict__ b, const float* __restrict__ c, float* __restrict__ out)
{
  const int i = blockIdx.x*256 + threadIdx.x;
  if (i >= QKVS) return;
  out[i] = (i < 768) ? a[i] : ((i < 1536) ? b[i - 768] : c[i - 1536]);
}

// ---------------- weight transpose+convert: fp32 [K][N] -> bf16 [N][K] ----------------
__global__ __launch_bounds__(256) void transpose_w(const float* __restrict__ W,
    bf16* __restrict__ out, int K, int N)
{
  __shared__ float tile[32][33];
  const int gk = blockIdx.y*32, gn = blockIdx.x*32;
  const int tr = threadIdx.x >> 5, tc = threadIdx.x & 31;
  #pragma unroll
  for (int i = 0; i < 4; i++)
    tile[tr + i*8][tc] = W[(size_t)(gk + tr + i*8)*N + gn + tc];
  __syncthreads();
  #pragma unroll
  for (int i = 0; i < 4; i++)
    out[(size_t)(gn + tr + i*8)*K + gk + tc] = __float2bfloat16(tile[tc][tr + i*8]);
}

// ---------------- MFMA GEMM with async global->LDS staging ----------------
template<int ACT, int RESID, int BF16OUT>
__global__ __launch_bounds__(256) void mfma_gemm_k(const bf16* __restrict__ A,
    const bf16* __restrict__ Bt, const float* __restrict__ bias,
    const float* __restrict__ resid, void* __restrict__ Cout, int M, int N, int K)
{
  __shared__ uint4 Alds[512];
  __shared__ uint4 Blds[512];

  const int tid = threadIdx.x;
  const int wid = tid >> 6, lane = tid & 63;
  const int wr = wid >> 1, wc = wid & 1;
  const int bm = blockIdx.y*128, bn = blockIdx.x*128;

  const int g0 = tid >> 7;
  const int r0 = tid & 127;
  const int arow = min(bm + r0, M-1);
  const int brow = min(bn + r0, N-1);
  const int lg = lane >> 4, lr = lane & 15;

  const bf16* aptr = A  + (size_t)arow*K + g0*8;
  const bf16* bptr = Bt + (size_t)brow*K + g0*8;
  uint4* adst0 = &Alds[g0*128 + r0];
  uint4* adst1 = &Alds[(g0+2)*128 + r0];
  uint4* bdst0 = &Blds[g0*128 + r0];
  uint4* bdst1 = &Blds[(g0+2)*128 + r0];

  f32x4 acc[4][4];
  #pragma unroll
  for (int i = 0; i < 4; i++)
    #pragma unroll
    for (int j = 0; j < 4; j++)
      acc[i][j] = (f32x4){0.f,0.f,0.f,0.f};

  for (int k0 = 0; k0 < K; k0 += 32){
    __syncthreads();
    gload_lds16(aptr + k0,      adst0);
    gload_lds16(aptr + k0 + 16, adst1);
    gload_lds16(bptr + k0,      bdst0);
    gload_lds16(bptr + k0 + 16, bdst1);
    __syncthreads();

    bf16x8 af[4], bfr[4];
    #pragma unroll
    for (int mf = 0; mf < 4; mf++)
      af[mf] = *reinterpret_cast<const bf16x8*>(&Alds[lg*128 + wr*64 + mf*16 + lr]);
    #pragma unroll
    for (int nf = 0; nf < 4; nf++)
      bfr[nf] = *reinterpret_cast<const bf16x8*>(&Blds[lg*128 + wc*64 + nf*16 + lr]);

    #pragma unroll
    for (int mf = 0; mf < 4; mf++)
      #pragma unroll
      for (int nf = 0; nf < 4; nf++)
        acc[mf][nf] = __builtin_amdgcn_mfma_f32_16x16x32_bf16(af[mf], bfr[nf], acc[mf][nf], 0, 0, 0);
  }

  #pragma unroll
  for (int mf = 0; mf < 4; mf++){
    #pragma unroll
    for (int rg = 0; rg < 4; rg++){
      const int row = bm + wr*64 + mf*16 + (lane>>4)*4 + rg;
      if (row >= M) continue;
      #pragma unroll
      for (int nf = 0; nf < 4; nf++){
        const int col = bn + wc*64 + nf*16 + (lane&15);
        if (col >= N) continue;
        float v = acc[mf][nf][rg] + bias[col];
        if (ACT == 1) v = geluf(v);
        if (RESID)    v += resid[(size_t)row*N + col];
        if (BF16OUT)  reinterpret_cast<bf16*>(Cout)[(size_t)row*N + col] = __float2bfloat16(v);
        else          reinterpret_cast<float*>(Cout)[(size_t)row*N + col] = v;
      }
    }
  }
}

// ---------------- LayerNorm over D=768: fp32 in -> bf16 out ----------------
__global__ __launch_bounds__(256) void layernorm_k(const float* __restrict__ x,
    const float* __restrict__ g, const float* __restrict__ bb, bf16* __restrict__ out)
{
  const int row = blockIdx.x;
  const float* xr = x + (size_t)row*D_;
  const int tid = threadIdx.x;
  const float v0 = xr[tid], v1 = xr[tid+256], v2 = xr[tid+512];

  float s = v0 + v1 + v2;
  #pragma unroll
  for (int o = 32; o > 0; o >>= 1) s += __shfl_xor(s, o);
  __shared__ float sm[4];
  const int wid = tid >> 6, lane = tid & 63;
  if (lane == 0) sm[wid] = s;
  __syncthreads();
  const float mean = (sm[0]+sm[1]+sm[2]+sm[3]) * (1.f/768.f);
  __syncthreads();

  const float d0 = v0-mean, d1 = v1-mean, d2 = v2-mean;
  float ss = d0*d0 + d1*d1 + d2*d2;
  #pragma unroll
  for (int o = 32; o > 0; o >>= 1) ss += __shfl_xor(ss, o);
  if (lane == 0) sm[wid] = ss;
  __syncthreads();
  const float var = (sm[0]+sm[1]+sm[2]+sm[3]) * (1.f/768.f);
  const float inv = rsqrtf(var + 1e-5f);

  bf16* orow = out + (size_t)row*D_;
  orow[tid]     = __float2bfloat16(d0*inv*g[tid]     + bb[tid]);
  orow[tid+256] = __float2bfloat16(d1*inv*g[tid+256] + bb[tid+256]);
  orow[tid+512] = __float2bfloat16(d2*inv*g[tid+512] + bb[tid+512]);
}

// ---------------- flash attention: MFMA QK^T + MFMA PV, bank-swizzled V and S ----------------
// srel[q,k]: k<=q -> qer[q-q0][499-(q-k)] ; k==q+1 -> 0 ; k>q+1 -> qer[q-q0+1][k-q-2]
// V swizzle:  col' = col ^ (((row>>3)&3)<<4)  (16B-chunk-preserving)
// S swizzle:  col' = col ^ ((row&7)<<2)       (float4-chunk-preserving)
__global__ __launch_bounds__(256) void flash_attn_k(const bf16* __restrict__ qkv,
    const bf16* __restrict__ erb, bf16* __restrict__ ob)
{
  const int b = blockIdx.y / NH_, h = blockIdx.y % NH_;
  const int q0 = blockIdx.x * 16;
  const int tid = threadIdx.x;
  const int w = tid >> 6, lane = tid & 63;
  const int lr = lane & 15, lg = lane >> 4;

  __shared__ unsigned short qer_l[17][520];   // 17.7 KB bf16 qer
  __shared__ unsigned short vs_u[64][72];     // 9.2 KB V superblock (bf16, swizzled)
  __shared__ float S_f[16][68];               // 4.3 KB S tile (swizzled)
  __shared__ float tmax_lds[4][16];

  const bf16* qbase = qkv + h*DH_;
  const bf16* kbase = qkv + 768 + h*DH_;
  const bf16* vbase = qkv + 1536 + h*DH_;

  // ---- Q fragment (rows q0..q0+15) ----
  int qq0 = q0 + lr; if (qq0 > 499) qq0 = 499;
  bf16x8 qf[2];
  #pragma unroll
  for (int h2 = 0; h2 < 2; h2++)
    qf[h2] = *reinterpret_cast<const bf16x8*>(qbase + (size_t)(b*T_ + qq0)*QKVS + h2*32 + lg*8);

  // ---- qer[r][c] = Q[q0+r]·er[c], rows 0..16, via MFMA ----
  {
    int qq1 = q0 + 16 + lr; if (qq1 > 499) qq1 = 499;
    bf16x8 a1f[2];
    #pragma unroll
    for (int h2 = 0; h2 < 2; h2++)
      a1f[h2] = *reinterpret_cast<const bf16x8*>(qbase + (size_t)(b*T_ + qq1)*QKVS + h2*32 + lg*8);
    for (int ct = w; ct < 32; ct += 4){
      const int c0 = ct*16;
      int cc = c0 + lr; if (cc > 499) cc = 499;
      bf16x8 bw[2];
      #pragma unroll
      for (int h2 = 0; h2 < 2; h2++)
        bw[h2] = *reinterpret_cast<const bf16x8*>(erb + (size_t)cc*DH_ + h2*32 + lg*8);
      f32x4 c0a = (f32x4){0,0,0,0}, c1a = (f32x4){0,0,0,0};
      c0a = __builtin_amdgcn_mfma_f32_16x16x32_bf16(qf[0],  bw[0], c0a, 0, 0, 0);
      c0a = __builtin_amdgcn_mfma_f32_16x16x32_bf16(qf[1],  bw[1], c0a, 0, 0, 0);
      c1a = __builtin_amdgcn_mfma_f32_16x16x32_bf16(a1f[0], bw[0], c1a, 0, 0, 0);
      c1a = __builtin_amdgcn_mfma_f32_16x16x32_bf16(a1f[1], bw[1], c1a, 0, 0, 0);
      #pragma unroll
      for (int rg = 0; rg < 4; rg++)
        qer_l[lg*4 + rg][c0 + lr] = __bfloat16_as_ushort(__float2bfloat16(c0a[rg]));
      if (lg == 0) qer_l[16][c0 + lr] = __bfloat16_as_ushort(__float2bfloat16(c1a[0]));
    }
  }

  // ---- initial V stage: superblock 0 (bf16, swizzled chunks) ----
  const int skr = tid >> 2;            // 0..63 (k row)
  const int sc  = (tid & 3) * 16;      // d group
  const int swc = sc ^ (((skr >> 3) & 3) << 4);
  {
    const int krow = min(skr, 499);
    const bf16* vp = vbase + (size_t)(b*T_ + krow)*QKVS + sc;
    const uint4 u01 = *reinterpret_cast<const uint4*>(vp);
    const uint4 u23 = *reinterpret_cast<const uint4*>(vp + 8);
    *reinterpret_cast<uint4*>(&vs_u[skr][swc])     = u01;
    *reinterpret_cast<uint4*>(&vs_u[skr][swc + 8]) = u23;
  }
  __syncthreads();

  float m_q = -3.0e38f, l_q = 0.f;     // per-lane stats for q = q0 + lr
  f32x4 acc = (f32x4){0.f,0.f,0.f,0.f};// C: row q'=lg*4+rg, col d = w*16 + lr
  const int vcol = (w*16 + lr) ^ (lg << 4);   // swizzled V read column

  for (int sb = 0; sb < 8; sb++){
    const int K0 = sb*64;
    const bool pf = (sb < 7);
    uint4 pva, pvb;
    if (pf){
      const int krow = min(K0 + 64 + skr, 499);
      const bf16* vp = vbase + (size_t)(b*T_ + krow)*QKVS + sc;
      pva = *reinterpret_cast<const uint4*>(vp);
      pvb = *reinterpret_cast<const uint4*>(vp + 8);
    }

    // ---- QK^T: wave w computes S for k-tile K0 + w*16 ----
    const int k0 = K0 + w*16;
    int kk = k0 + lr; if (kk > 499) kk = 499;
    bf16x8 kf[2];
    #pragma unroll
    for (int h2 = 0; h2 < 2; h2++)
      kf[h2] = *reinterpret_cast<const bf16x8*>(kbase + (size_t)(b*T_ + kk)*QKVS + h2*32 + lg*8);
    f32x4 sacc = (f32x4){0,0,0,0};
    sacc = __builtin_amdgcn_mfma_f32_16x16x32_bf16(qf[0], kf[0], sacc, 0, 0, 0);
    sacc = __builtin_amdgcn_mfma_f32_16x16x32_bf16(qf[1], kf[1], sacc, 0, 0, 0);

    const int kcol = k0 + lr;
    float sv[4], tm[4];
    #pragma unroll
    for (int rg = 0; rg < 4; rg++){
      const int r = lg*4 + rg;
      const int q = q0 + r;
      float d2 = 0.f;
      if (kcol != q + 1){
        const int eidx = (kcol <= q) ? (499 - q + kcol) : (kcol - q - 2);
        d2 = bfu2f(qer_l[(kcol <= q) ? r : r + 1][eidx]);
      }
      float s = (sacc[rg] + d2) * 0.125f;
      if (kcol >= 500) s = -3.0e38f;
      sv[rg] = s;
      tm[rg] = s;
      #pragma unroll
      for (int o = 8; o > 0; o >>= 1) tm[rg] = fmaxf(tm[rg], __shfl_xor(tm[rg], o, 16));
    }
    #pragma unroll
    for (int rg = 0; rg < 4; rg++){
      const int r = lg*4 + rg;
      S_f[r][(w*16 + lr) ^ ((r & 7) << 2)] = sv[rg];
    }
    if (lr == 0){
      #pragma unroll
      for (int rg = 0; rg < 4; rg++) tmax_lds[w][lg*4 + rg] = tm[rg];
    }
    __syncthreads();    // S + tmax visible; V(current) still valid

    // ---- per-lane stats for q = lr ----
    const float tg = fmaxf(fmaxf(tmax_lds[0][lr], tmax_lds[1][lr]),
                           fmaxf(tmax_lds[2][lr], tmax_lds[3][lr]));
    const float mn = fmaxf(m_q, tg);
    const float corr = __expf(m_q - mn);
    m_q = mn;

    // ---- P-fragments: row lr, k = hh*32 + lg*8 + j ; exp + pack bf16 ----
    const int kx = (lr & 7) << 2;
    float psum = 0.f;
    bf16x8 pfr[2];
    #pragma unroll
    for (int hh = 0; hh < 2; hh++){
      const int cbase = (hh*32 + lg*8) ^ kx;
      const float4 sA = *reinterpret_cast<const float4*>(&S_f[lr][cbase]);
      const float4 sB = *reinterpret_cast<const float4*>(&S_f[lr][cbase ^ 4]);
      float p0 = __expf(sA.x - mn), p1 = __expf(sA.y - mn);
      float p2 = __expf(sA.z - mn), p3 = __expf(sA.w - mn);
      float p4 = __expf(sB.x - mn), p5 = __expf(sB.y - mn);
      float p6 = __expf(sB.z - mn), p7 = __expf(sB.w - mn);
      psum += ((p0+p1)+(p2+p3)) + ((p4+p5)+(p6+p7));
      bf16x8 pk;
      pk[0] = (short)__bfloat16_as_ushort(__float2bfloat16(p0));
      pk[1] = (short)__bfloat16_as_ushort(__float2bfloat16(p1));
      pk[2] = (short)__bfloat16_as_ushort(__float2bfloat16(p2));
      pk[3] = (short)__bfloat16_as_ushort(__float2bfloat16(p3));
      pk[4] = (short)__bfloat16_as_ushort(__float2bfloat16(p4));
      pk[5] = (short)__bfloat16_as_ushort(__float2bfloat16(p5));
      pk[6] = (short)__bfloat16_as_ushort(__float2bfloat16(p6));
      pk[7] = (short)__bfloat16_as_ushort(__float2bfloat16(p7));
      pfr[hh] = pk;
    }
    psum += __shfl_xor(psum, 16);
    psum += __shfl_xor(psum, 32);
    l_q = l_q*corr + psum;

    // ---- rescale acc rows by their corr (row q' = lg*4+rg) ----
    #pragma unroll
    for (int rg = 0; rg < 4; rg++){
      const float cr = __shfl(corr, lg*4 + rg, 16);
      acc[rg] *= cr;
    }

    // ---- PV: acc += P(16q x 32k) x V(32k x 16d), two K=32 MFMAs ----
    #pragma unroll
    for (int hh = 0; hh < 2; hh++){
      bf16x8 vf;
      #pragma unroll
      for (int j = 0; j < 8; j++)
        vf[j] = (short)vs_u[hh*32 + lg*8 + j][vcol];
      acc = __builtin_amdgcn_mfma_f32_16x16x32_bf16(pfr[hh], vf, acc, 0, 0, 0);
    }

    __syncthreads();    // all S/V reads for sb done
    if (pf){
      *reinterpret_cast<uint4*>(&vs_u[skr][swc])     = pva;
      *reinterpret_cast<uint4*>(&vs_u[skr][swc + 8]) = pvb;
    }
  }

  // ---- output: row q' = lg*4+rg, col d = w*16 + lr ----
  #pragma unroll
  for (int rg = 0; rg < 4; rg++){
    const int qp = lg*4 + rg;
    const int q = q0 + qp;
    if (q < T_){
      const float lrow = __shfl(l_q, qp, 16);
      ob[((size_t)(b*T_ + q))*D_ + h*DH_ + w*16 + lr] = __float2bfloat16(acc[rg] / lrow);
    }
  }
}

// =====================================================================
extern "C" void kernel_launch(void* const* d_in, const int* in_sizes, int n_in,
                              void* d_out, int out_size, void* d_ws, size_t ws_size,
                              hipStream_t stream)
{
  const float* spec  = (const float*)d_in[0];
  const float* cw1 = (const float*)d_in[1];  const float* cb1 = (const float*)d_in[2];
  const float* cw2 = (const float*)d_in[3];  const float* cb2 = (const float*)d_in[4];
  const float* cw3 = (const float*)d_in[5];  const float* cb3 = (const float*)d_in[6];
  const float* cw4 = (const float*)d_in[7];  const float* cb4 = (const float*)d_in[8];
  const float* proj_w = (const float*)d_in[9];  const float* proj_b = (const float*)d_in[10];
  const float* ln1_g = (const float*)d_in[11];  const float* ln1_b = (const float*)d_in[12];
  const float* wq = (const float*)d_in[13];  const float* bq = (const float*)d_in[14];
  const float* wk = (const float*)d_in[15];  const float* bk = (const float*)d_in[16];
  const float* wv = (const float*)d_in[17];  const float* bv = (const float*)d_in[18];
  const float* wo = (const float*)d_in[19];  const float* bo = (const float*)d_in[20];
  const float* er = (const float*)d_in[21];
  const float* ln2_g = (const float*)d_in[22];  const float* ln2_b = (const float*)d_in[23];
  const float* w1 = (const float*)d_in[24];  const float* b1 = (const float*)d_in[25];
  const float* w2 = (const float*)d_in[26];  const float* b2 = (const float*)d_in[27];
  const float* dw = (const float*)d_in[28];  const float* db = (const float*)d_in[29];

  if (ws_size < 98304000ull) return;
  char* W = (char*)d_ws;
  bf16*  n1 = (bf16*) (W + 0);
  bf16*  n2 = (bf16*) (W + 49152000);
  bf16*  n3 = (bf16*) (W + 0);
  bf16*  n4 = (bf16*) (W + 24576000);
  bf16*  tk = (bf16*) (W + 49152000);
  float* xb = (float*)(W + 0);
  bf16*  xn = (bf16*) (W + 24576000);
  bf16*  qkv= (bf16*) (W + 36864000);
  bf16*  ob = (bf16*) (W + 73728000);
  bf16*  hb = (bf16*) (W + 36864000);
  bf16*  wt = (bf16*) (W + 86016000);
  bf16*  erb= (bf16*) (W + 92274688);
  float* qkvb=(float*)(W + 92340224);
  bf16* cwt2 = (bf16*)d_out;
  bf16* cwt3 = (bf16*)((char*)d_out + 262144);
  bf16* cwt4 = (bf16*)((char*)d_out + 786432);

  // ---- CNN stack (NHWC, MFMA for conv2-4) ----
  conv_wt_k<32><<<(25*32*64 + 255)/256, 256, 0, stream>>>(cw2, cwt2);
  conv_wt_k<64><<<(25*64*64 + 255)/256, 256, 0, stream>>>(cw3, cwt3);
  conv_wt_k<64><<<(25*64*64 + 255)/256, 256, 0, stream>>>(cw4, cwt4);

  conv1_k<<<(B_*96*500 + 255)/256, 256, 0, stream>>>(spec, cw1, cb1, n1);
  conv_mfma_k<32><<<dim3(8, B_*48), 256, 0, stream>>>(n1, cwt2, cb2, n2, 96);
  conv_mfma_k<64><<<dim3(8, B_*24), 256, 0, stream>>>(n2, cwt3, cb3, n3, 48);
  conv_mfma_k<64><<<dim3(8, B_*12), 256, 0, stream>>>(n3, cwt4, cb4, n4, 24);

  tokens_k<<<(B_*12*500*64 + 255)/256, 256, 0, stream>>>(n4, tk);

  transpose_w<<<dim3(D_/32, D_/32), 256, 0, stream>>>(proj_w, wt, D_, D_);
  mfma_gemm_k<0,0,0><<<dim3(6,63), 256, 0, stream>>>(tk, wt, proj_b, nullptr, xb, 8000, D_, D_);

  // ---- transformer layers ----
  for (int l = 0; l < 3; l++){
    const size_t wOff = (size_t)l*D_*D_;
    layernorm_k<<<8000, 256, 0, stream>>>(xb, ln1_g + l*D_, ln1_b + l*D_, xn);

    transpose_w<<<dim3(D_/32, D_/32), 256, 0, stream>>>(wq + wOff, wt,            D_, D_);
    transpose_w<<<dim3(D_/32, D_/32), 256, 0, stream>>>(wk + wOff, wt + 589824,   D_, D_);
    transpose_w<<<dim3(D_/32, D_/32), 256, 0, stream>>>(wv + wOff, wt + 1179648,  D_, D_);
    pack3_k<<<(QKVS + 255)/256, 256, 0, stream>>>(bq + l*D_, bk + l*D_, bv + l*D_, qkvb);
    mfma_gemm_k<0,0,1><<<dim3(18,63), 256, 0, stream>>>(xn, wt, qkvb, nullptr, qkv, 8000, QKVS, D_);

    er2bf_k<<<(T_*DH_ + 255)/256, 256, 0, stream>>>(er + (size_t)l*T_*DH_, erb);
    flash_attn_k<<<dim3(32, B_*NH_), 256, 0, stream>>>(qkv, erb, ob);

    transpose_w<<<dim3(D_/32, D_/32), 256, 0, stream>>>(wo + wOff, wt, D_, D_);
    mfma_gemm_k<0,1,0><<<dim3(6,63), 256, 0, stream>>>(ob, wt, bo + l*D_, xb, xb, 8000, D_, D_);

    layernorm_k<<<8000, 256, 0, stream>>>(xb, ln2_g + l*D_, ln2_b + l*D_, xn);

    transpose_w<<<dim3(FFN_/32, D_/32), 256, 0, stream>>>(w1 + (size_t)l*D_*FFN_, wt, D_, FFN_);
    mfma_gemm_k<1,0,1><<<dim3(24,63), 256, 0, stream>>>(xn, wt, b1 + l*FFN_, nullptr, hb, 8000, FFN_, D_);
    transpose_w<<<dim3(D_/32, FFN_/32), 256, 0, stream>>>(w2 + (size_t)l*FFN_*D_, wt, FFN_, D_);
    mfma_gemm_k<0,1,0><<<dim3(6,63), 256, 0, stream>>>(hb, wt, b2 + l*D_, xb, xb, 8000, D_, FFN_);
  }

  // ---- deproj via MFMA -> fp32 output [8000, 192] ----
  f2bf_k<<<(8000*D_/4 + 255)/256, 256, 0, stream>>>(xb, xn, 8000*D_/4);
  transpose_w<<<dim3(192/32, D_/32), 256, 0, stream>>>(dw, wt, D_, 192);
  mfma_gemm_k<0,0,0><<<dim3(2,63), 256, 0, stream>>>(xn, wt, db, nullptr, d_out, 8000, 192, D_);
}